// Round 14
// baseline (344.958 us; speedup 1.0000x reference)
//
#include <hip/hip_runtime.h>

#define BB 32
#define TT 2048
#define CC 64
#define BT (BB * TT)
#define NCH 128
#define CL 16  // chunk length; NCH*CL == TT
#define GN_EPS (1e-5f * 64.f)

typedef short short8 __attribute__((ext_vector_type(8)));
typedef float f32x4 __attribute__((ext_vector_type(4)));

// ---- cross-lane helpers --------------------------------------------------
__device__ __forceinline__ float rl(float v, int lane) {
  return __uint_as_float(__builtin_amdgcn_readlane(__float_as_uint(v), lane));
}
template <int CTRL>
__device__ __forceinline__ float dppadd(float x) {
  return x + __int_as_float(__builtin_amdgcn_update_dpp(
                 0, __float_as_int(x), CTRL, 0xf, 0xf, true));
}
__device__ __forceinline__ float wave_red_sum(float x) {
  x = dppadd<0x111>(x);
  x = dppadd<0x112>(x);
  x = dppadd<0x114>(x);
  x = dppadd<0x118>(x);
  x = dppadd<0x142>(x);
  x = dppadd<0x143>(x);
  return __uint_as_float(__builtin_amdgcn_readlane(__float_as_uint(x), 63));
}
__device__ __forceinline__ float tanh_f(float x) {
  x = fminf(fmaxf(x, -10.f), 10.f);
  const float e = __expf(2.f * x);
  return (e - 1.f) / (e + 1.f);
}

// ---- bf16 helpers --------------------------------------------------------
__device__ __forceinline__ unsigned short f2bf(float x) {
  unsigned int u = __float_as_uint(x);
  u += 0x7FFFu + ((u >> 16) & 1u);   // RNE
  return (unsigned short)(u >> 16);
}
__device__ __forceinline__ float bf2f(unsigned short h) {
  return __uint_as_float(((unsigned int)h) << 16);
}
__device__ __forceinline__ short8 cvt8(const float4 a, const float4 b) {
  short8 h;
  h[0] = (short)f2bf(a.x); h[1] = (short)f2bf(a.y);
  h[2] = (short)f2bf(a.z); h[3] = (short)f2bf(a.w);
  h[4] = (short)f2bf(b.x); h[5] = (short)f2bf(b.y);
  h[6] = (short)f2bf(b.z); h[7] = (short)f2bf(b.w);
  return h;
}
__device__ __forceinline__ short8 ldb8(const float* __restrict__ p) {
  const float4 v0 = *reinterpret_cast<const float4*>(p);
  const float4 v1 = *reinterpret_cast<const float4*>(p + 4);
  return cvt8(v0, v1);
}
__device__ __forceinline__ short8 ldb8_lds(const float* p) {
  const float4 v0 = *reinterpret_cast<const float4*>(p);
  const float4 v1 = *reinterpret_cast<const float4*>(p + 4);
  return cvt8(v0, v1);
}

// ---- preT: transpose tiny weights for contiguous B-fragments -------------
__global__ __launch_bounds__(256) void preT_kernel(
    const float* __restrict__ maa_w1, const float* __restrict__ maa_w2,
    const float* __restrict__ dec_w1, const float* __restrict__ dec_w2,
    float* __restrict__ w1T, float* __restrict__ w2T,
    float* __restrict__ d1T, float* __restrict__ d2T)
{
  const int t0 = blockIdx.x * 256 + threadIdx.x;
  const int stride = gridDim.x * 256;
  for (int i = t0; i < 160 * 64; i += stride) {
    const int n = i >> 6, c = i & 63;
    w1T[i] = maa_w1[c * 160 + n];               // w1T[n][c]
  }
  for (int i = t0; i < 5 * 64 * 32; i += stride) {
    const int f = i >> 11, rem = i & 2047, n = rem >> 5, q = rem & 31;
    w2T[i] = maa_w2[(f * 32 + q) * 64 + n];     // w2T[f][n][q]
  }
  for (int i = t0; i < 4096; i += stride) {
    const int n = i >> 6, c = i & 63;
    d1T[i] = dec_w1[c * 64 + n];                // d1T[n][c]
    d2T[i] = dec_w2[c * 64 + n];                // d2T[n][q]
  }
}

// ---- mix via MFMA: token-shift + maa mixing + decay MLP ------------------
#define LDS_A 36
#define LDS_X 68
__global__ __launch_bounds__(256) void mix_mfma_kernel(
    const float* __restrict__ x,
    const float* __restrict__ tm_x, const float* __restrict__ tm_w, const float* __restrict__ tm_k,
    const float* __restrict__ tm_v, const float* __restrict__ tm_r, const float* __restrict__ tm_g,
    const float* __restrict__ w1T, const float* __restrict__ w2T,
    const float* __restrict__ d1T, const float* __restrict__ d2T,
    const float* __restrict__ t_decay,
    float* __restrict__ xk_o, float* __restrict__ xv_o,
    float* __restrict__ xr_o, float* __restrict__ xg_o,
    float* __restrict__ rkdc)
{
  __shared__ float aT[4][32][LDS_A];   // per-wave a-transpose (32x32 used)
  __shared__ float xT[4][32][LDS_X];   // per-wave xw / h transpose (32x64)
  const int lane = threadIdx.x & 63;
  const int wid = threadIdx.x >> 6;
  const int col = lane & 15, half = lane >> 4;
  const int tok0 = blockIdx.x * 128 + wid * 32;

  short8 xa[2][2];
#pragma unroll
  for (int m = 0; m < 2; ++m)
#pragma unroll
    for (int kk = 0; kk < 2; ++kk) {
      const int tok = tok0 + m * 16 + col;
      const int kb = kk * 32 + half * 8;
      const float* pc = x + (size_t)tok * CC + kb;
      const float4 c0 = *reinterpret_cast<const float4*>(pc);
      const float4 c1 = *reinterpret_cast<const float4*>(pc + 4);
      float4 p0 = {0.f, 0.f, 0.f, 0.f}, p1 = {0.f, 0.f, 0.f, 0.f};
      if ((tok & (TT - 1)) != 0) {
        p0 = *reinterpret_cast<const float4*>(pc - CC);
        p1 = *reinterpret_cast<const float4*>(pc - CC + 4);
      }
      const float4 t0 = *reinterpret_cast<const float4*>(tm_x + kb);
      const float4 t1 = *reinterpret_cast<const float4*>(tm_x + kb + 4);
      const float cv[8] = {c0.x, c0.y, c0.z, c0.w, c1.x, c1.y, c1.z, c1.w};
      const float pv[8] = {p0.x, p0.y, p0.z, p0.w, p1.x, p1.y, p1.z, p1.w};
      const float tv[8] = {t0.x, t0.y, t0.z, t0.w, t1.x, t1.y, t1.z, t1.w};
      short8 h;
#pragma unroll
      for (int e = 0; e < 8; ++e)
        h[e] = (short)f2bf(fmaf(pv[e] - cv[e], tv[e], cv[e]));
      xa[m][kk] = h;
    }

  float xcv[2][4][4], xxv[2][4][4];
#pragma unroll
  for (int m = 0; m < 2; ++m)
#pragma unroll
    for (int reg = 0; reg < 4; ++reg) {
      const int tok = tok0 + m * 16 + half * 4 + reg;
      const bool has = (tok & (TT - 1)) != 0;
#pragma unroll
      for (int nt = 0; nt < 4; ++nt) {
        const size_t o = (size_t)tok * CC + nt * 16 + col;
        const float cur = x[o];
        const float prv = has ? x[o - CC] : 0.f;
        xcv[m][nt][reg] = cur;
        xxv[m][nt][reg] = prv - cur;
      }
    }

  auto process_f = [&](int f, const float* __restrict__ tmf,
                       float* __restrict__ gout) {
    f32x4 acc1[2][2];
#pragma unroll
    for (int m = 0; m < 2; ++m)
#pragma unroll
      for (int ntf = 0; ntf < 2; ++ntf) acc1[m][ntf] = (f32x4){0.f, 0.f, 0.f, 0.f};
    short8 b1[2][2];
#pragma unroll
    for (int ntf = 0; ntf < 2; ++ntf)
#pragma unroll
      for (int kk = 0; kk < 2; ++kk)
        b1[ntf][kk] = ldb8(w1T + (size_t)(f * 32 + ntf * 16 + col) * 64 + kk * 32 + half * 8);
#pragma unroll
    for (int m = 0; m < 2; ++m)
#pragma unroll
      for (int ntf = 0; ntf < 2; ++ntf)
#pragma unroll
        for (int kk = 0; kk < 2; ++kk)
          acc1[m][ntf] = __builtin_amdgcn_mfma_f32_16x16x32_bf16(
              xa[m][kk], b1[ntf][kk], acc1[m][ntf], 0, 0, 0);
#pragma unroll
    for (int m = 0; m < 2; ++m)
#pragma unroll
      for (int ntf = 0; ntf < 2; ++ntf)
#pragma unroll
        for (int reg = 0; reg < 4; ++reg)
          aT[wid][m * 16 + half * 4 + reg][ntf * 16 + col] = tanh_f(acc1[m][ntf][reg]);
    short8 a2[2];
#pragma unroll
    for (int m = 0; m < 2; ++m)
      a2[m] = ldb8_lds(&aT[wid][m * 16 + col][half * 8]);
    f32x4 acc2[2][4];
#pragma unroll
    for (int m = 0; m < 2; ++m)
#pragma unroll
      for (int nt = 0; nt < 4; ++nt) acc2[m][nt] = (f32x4){0.f, 0.f, 0.f, 0.f};
    short8 b2[4];
#pragma unroll
    for (int nt = 0; nt < 4; ++nt)
      b2[nt] = ldb8(w2T + (size_t)f * 2048 + (nt * 16 + col) * 32 + half * 8);
#pragma unroll
    for (int m = 0; m < 2; ++m)
#pragma unroll
      for (int nt = 0; nt < 4; ++nt)
        acc2[m][nt] = __builtin_amdgcn_mfma_f32_16x16x32_bf16(
            a2[m], b2[nt], acc2[m][nt], 0, 0, 0);
    float tmf4[4];
#pragma unroll
    for (int nt = 0; nt < 4; ++nt) tmf4[nt] = tmf[nt * 16 + col];
#pragma unroll
    for (int m = 0; m < 2; ++m)
#pragma unroll
      for (int nt = 0; nt < 4; ++nt)
#pragma unroll
        for (int reg = 0; reg < 4; ++reg) {
          const float val = fmaf(xxv[m][nt][reg], tmf4[nt] + acc2[m][nt][reg],
                                 xcv[m][nt][reg]);
          if (gout)
            gout[(size_t)(tok0 + m * 16 + half * 4 + reg) * CC + nt * 16 + col] = val;
          else
            xT[wid][m * 16 + half * 4 + reg][nt * 16 + col] = val;
        }
  };

  process_f(1, tm_k, xk_o);
  process_f(2, tm_v, xv_o);
  process_f(3, tm_r, xr_o);
  process_f(4, tm_g, xg_o);
  process_f(0, tm_w, nullptr);   // xw -> LDS xT

  short8 xwf[2][2];
#pragma unroll
  for (int m = 0; m < 2; ++m)
#pragma unroll
    for (int kk = 0; kk < 2; ++kk)
      xwf[m][kk] = ldb8_lds(&xT[wid][m * 16 + col][kk * 32 + half * 8]);
  f32x4 hcc[2][4];
#pragma unroll
  for (int m = 0; m < 2; ++m)
#pragma unroll
    for (int nt = 0; nt < 4; ++nt) hcc[m][nt] = (f32x4){0.f, 0.f, 0.f, 0.f};
  short8 bd[4][2];
#pragma unroll
  for (int nt = 0; nt < 4; ++nt)
#pragma unroll
    for (int kk = 0; kk < 2; ++kk)
      bd[nt][kk] = ldb8(d1T + (size_t)(nt * 16 + col) * 64 + kk * 32 + half * 8);
#pragma unroll
  for (int m = 0; m < 2; ++m)
#pragma unroll
    for (int nt = 0; nt < 4; ++nt)
#pragma unroll
      for (int kk = 0; kk < 2; ++kk)
        hcc[m][nt] = __builtin_amdgcn_mfma_f32_16x16x32_bf16(
            xwf[m][kk], bd[nt][kk], hcc[m][nt], 0, 0, 0);
#pragma unroll
  for (int m = 0; m < 2; ++m)
#pragma unroll
    for (int nt = 0; nt < 4; ++nt)
#pragma unroll
      for (int reg = 0; reg < 4; ++reg)
        xT[wid][m * 16 + half * 4 + reg][nt * 16 + col] = tanh_f(hcc[m][nt][reg]);
  short8 hf[2][2];
#pragma unroll
  for (int m = 0; m < 2; ++m)
#pragma unroll
    for (int kk = 0; kk < 2; ++kk)
      hf[m][kk] = ldb8_lds(&xT[wid][m * 16 + col][kk * 32 + half * 8]);
  f32x4 wfa[2][4];
#pragma unroll
  for (int m = 0; m < 2; ++m)
#pragma unroll
    for (int nt = 0; nt < 4; ++nt) wfa[m][nt] = (f32x4){0.f, 0.f, 0.f, 0.f};
#pragma unroll
  for (int nt = 0; nt < 4; ++nt)
#pragma unroll
    for (int kk = 0; kk < 2; ++kk)
      bd[nt][kk] = ldb8(d2T + (size_t)(nt * 16 + col) * 64 + kk * 32 + half * 8);
#pragma unroll
  for (int m = 0; m < 2; ++m)
#pragma unroll
    for (int nt = 0; nt < 4; ++nt)
#pragma unroll
      for (int kk = 0; kk < 2; ++kk)
        wfa[m][nt] = __builtin_amdgcn_mfma_f32_16x16x32_bf16(
            hf[m][kk], bd[nt][kk], wfa[m][nt], 0, 0, 0);
  float td4[4];
#pragma unroll
  for (int nt = 0; nt < 4; ++nt) td4[nt] = t_decay[nt * 16 + col];
#pragma unroll
  for (int m = 0; m < 2; ++m)
#pragma unroll
    for (int nt = 0; nt < 4; ++nt)
#pragma unroll
      for (int reg = 0; reg < 4; ++reg)
        rkdc[4 * ((size_t)(tok0 + m * 16 + half * 4 + reg) * CC + nt * 16 + col) + 2] =
            __expf(-__expf(wfa[m][nt][reg] + td4[nt]));
}

// ---- proj4 via MFMA (bf16 3-product split) -------------------------------
__device__ __forceinline__ void load_afrag(
    const float* __restrict__ X, int tok0, int col, int half,
    short8 ah[2][2], short8 al[2][2])
{
#pragma unroll
  for (int m = 0; m < 2; ++m)
#pragma unroll
    for (int kk = 0; kk < 2; ++kk) {
      const float* p = X + (size_t)(tok0 + m * 16 + col) * CC + kk * 32 + half * 8;
      const float4 v0 = *reinterpret_cast<const float4*>(p);
      const float4 v1 = *reinterpret_cast<const float4*>(p + 4);
      const float vv[8] = {v0.x, v0.y, v0.z, v0.w, v1.x, v1.y, v1.z, v1.w};
      short8 h, l;
#pragma unroll
      for (int e = 0; e < 8; ++e) {
        const unsigned short hb = f2bf(vv[e]);
        h[e] = (short)hb;
        l[e] = (short)f2bf(vv[e] - bf2f(hb));
      }
      ah[m][kk] = h; al[m][kk] = l;
    }
}
__device__ __forceinline__ void load_bfrag(
    const float* __restrict__ W, int col, int half,
    short8 bh[4][2], short8 bl[4][2])
{
#pragma unroll
  for (int n = 0; n < 4; ++n)
#pragma unroll
    for (int kk = 0; kk < 2; ++kk) {
      const float* p = W + (size_t)(n * 16 + col) * CC + kk * 32 + half * 8;
      const float4 v0 = *reinterpret_cast<const float4*>(p);
      const float4 v1 = *reinterpret_cast<const float4*>(p + 4);
      const float vv[8] = {v0.x, v0.y, v0.z, v0.w, v1.x, v1.y, v1.z, v1.w};
      short8 h, l;
#pragma unroll
      for (int e = 0; e < 8; ++e) {
        const unsigned short hb = f2bf(vv[e]);
        h[e] = (short)hb;
        l[e] = (short)f2bf(vv[e] - bf2f(hb));
      }
      bh[n][kk] = h; bl[n][kk] = l;
    }
}
__device__ __forceinline__ void gemm_acc(
    const short8 ah[2][2], const short8 al[2][2],
    const short8 bh[4][2], const short8 bl[4][2], f32x4 acc[2][4])
{
#pragma unroll
  for (int m = 0; m < 2; ++m)
#pragma unroll
    for (int n = 0; n < 4; ++n) {
      f32x4 a = acc[m][n];
#pragma unroll
      for (int kk = 0; kk < 2; ++kk) {
        a = __builtin_amdgcn_mfma_f32_16x16x32_bf16(ah[m][kk], bh[n][kk], a, 0, 0, 0);
        a = __builtin_amdgcn_mfma_f32_16x16x32_bf16(ah[m][kk], bl[n][kk], a, 0, 0, 0);
        a = __builtin_amdgcn_mfma_f32_16x16x32_bf16(al[m][kk], bh[n][kk], a, 0, 0, 0);
      }
      acc[m][n] = a;
    }
}

__global__ __launch_bounds__(256) void proj4_mfma_kernel(
    const float* __restrict__ xk_i, const float* __restrict__ xv_i,
    const float* __restrict__ xr_i, const float* __restrict__ xg_i,
    const float* __restrict__ u,
    const float* __restrict__ Wr, const float* __restrict__ Wk, const float* __restrict__ Wv,
    const float* __restrict__ Wg,
    float* __restrict__ rkdc, float* __restrict__ v_o, float* __restrict__ g_o)
{
  const int lane = threadIdx.x & 63;
  const int wid = threadIdx.x >> 6;
  const int col = lane & 15, half = lane >> 4;
  const int tok0 = blockIdx.x * 128 + wid * 32;

  short8 ah[2][2], al[2][2], bh[4][2], bl[4][2];
  f32x4 accr[2][4], acck[2][4];

  load_bfrag(Wr, col, half, bh, bl);
  load_afrag(xr_i, tok0, col, half, ah, al);
#pragma unroll
  for (int m = 0; m < 2; ++m)
#pragma unroll
    for (int n = 0; n < 4; ++n) accr[m][n] = (f32x4){0.f, 0.f, 0.f, 0.f};
  gemm_acc(ah, al, bh, bl, accr);

  load_bfrag(Wk, col, half, bh, bl);
  load_afrag(xk_i, tok0, col, half, ah, al);
#pragma unroll
  for (int m = 0; m < 2; ++m)
#pragma unroll
    for (int n = 0; n < 4; ++n) acck[m][n] = (f32x4){0.f, 0.f, 0.f, 0.f};
  gemm_acc(ah, al, bh, bl, acck);

  float uv[4];
#pragma unroll
  for (int n = 0; n < 4; ++n) uv[n] = u[n * 16 + col];
  float ctv[2][4];
#pragma unroll
  for (int m = 0; m < 2; ++m)
#pragma unroll
    for (int reg = 0; reg < 4; ++reg) {
      float p = 0.f;
#pragma unroll
      for (int n = 0; n < 4; ++n)
        p += accr[m][n][reg] * uv[n] * acck[m][n][reg];
      p += __shfl_xor(p, 1, 64);
      p += __shfl_xor(p, 2, 64);
      p += __shfl_xor(p, 4, 64);
      p += __shfl_xor(p, 8, 64);
      ctv[m][reg] = p;
    }

#pragma unroll
  for (int m = 0; m < 2; ++m)
#pragma unroll
    for (int n = 0; n < 4; ++n)
#pragma unroll
      for (int reg = 0; reg < 4; ++reg) {
        const int token = tok0 + m * 16 + half * 4 + reg;
        const size_t o = (size_t)token * CC + n * 16 + col;
        rkdc[4 * o + 0] = accr[m][n][reg];
        rkdc[4 * o + 1] = acck[m][n][reg];
        rkdc[4 * o + 3] = ctv[m][reg];
      }

  load_bfrag(Wv, col, half, bh, bl);
  load_afrag(xv_i, tok0, col, half, ah, al);
#pragma unroll
  for (int m = 0; m < 2; ++m)
#pragma unroll
    for (int n = 0; n < 4; ++n) accr[m][n] = (f32x4){0.f, 0.f, 0.f, 0.f};
  gemm_acc(ah, al, bh, bl, accr);
#pragma unroll
  for (int m = 0; m < 2; ++m)
#pragma unroll
    for (int n = 0; n < 4; ++n)
#pragma unroll
      for (int reg = 0; reg < 4; ++reg) {
        const int token = tok0 + m * 16 + half * 4 + reg;
        v_o[(size_t)token * CC + n * 16 + col] = accr[m][n][reg];
      }

  load_bfrag(Wg, col, half, bh, bl);
  load_afrag(xg_i, tok0, col, half, ah, al);
#pragma unroll
  for (int m = 0; m < 2; ++m)
#pragma unroll
    for (int n = 0; n < 4; ++n) accr[m][n] = (f32x4){0.f, 0.f, 0.f, 0.f};
  gemm_acc(ah, al, bh, bl, accr);
#pragma unroll
  for (int m = 0; m < 2; ++m)
#pragma unroll
    for (int n = 0; n < 4; ++n)
#pragma unroll
      for (int reg = 0; reg < 4; ++reg) {
        const int token = tok0 + m * 16 + half * 4 + reg;
        const float gg = accr[m][n][reg];
        g_o[(size_t)token * CC + n * 16 + col] = gg / (1.f + __expf(-gg));
      }
}

// ---- A: chunk-local state ------------------------------------------------
__global__ __launch_bounds__(256) void chunkA_kernel(
    const float4* __restrict__ rkdc, const float* __restrict__ v_i,
    float* __restrict__ Sloc, float* __restrict__ Dp)
{
  const int lane = threadIdx.x & 63;
  const int bch = __builtin_amdgcn_readfirstlane((blockIdx.x << 2) + (threadIdx.x >> 6));
  const float4* fq = rkdc + (size_t)bch * (CL * CC);
  const float* dq = (const float*)fq + 4 * lane + 2;
  const float* vq = v_i + (size_t)bch * (CL * CC) + lane;

  float S[CC];
#pragma unroll
  for (int i = 0; i < CC; ++i) S[i] = 0.f;
  float dp = 1.f;

  for (int t = 0; t < CL; ++t) {
    const float4* ft = fq + t * CC;
    const float vv = vq[t * CC];
    dp *= dq[4 * t * CC];
#pragma unroll
    for (int i = 0; i < CC; ++i) {
      const float4 f = ft[i];
      S[i] = fmaf(f.z, S[i], f.y * vv);
    }
  }
  float* so = Sloc + (size_t)bch * (CC * CC) + lane;
#pragma unroll
  for (int i = 0; i < CC; ++i) so[i * CC] = S[i];
  Dp[(size_t)bch * CC + lane] = dp;
}

// ---- B: parallel combine: one thread per (b, i, j) element ---------------
__global__ __launch_bounds__(256) void combine_kernel(
    float* __restrict__ buf, const float* __restrict__ Dp)
{
  const int g = blockIdx.x * 256 + threadIdx.x;  // BB*4096 threads
  const int b = g >> 12;
  const int idx = g & 4095;
  const int i = idx >> 6;
  float run = 0.f;
  for (int ch = 0; ch < NCH; ++ch) {
    const size_t base = ((size_t)(b * NCH + ch)) * (CC * CC);
    const float tmp = buf[base + idx];
    buf[base + idx] = run;
    run = fmaf(run, Dp[((size_t)b * NCH + ch) * CC + i], tmp);
  }
}

// ---- C: emit + GroupNorm + *g + @Wo.T fused ------------------------------
__global__ __launch_bounds__(256) void scanC_kernel(
    const float4* __restrict__ rkdc, const float* __restrict__ v_i,
    const float* __restrict__ S0, const float* __restrict__ g_i,
    const float* __restrict__ ln_w, const float* __restrict__ ln_b,
    const float* __restrict__ Wo, float* __restrict__ out)
{
  __shared__ float WoT[4096];
  for (int idx = threadIdx.x; idx < 4096; idx += 256) {
    const int c = idx >> 6, jj = idx & 63;
    WoT[idx] = Wo[jj * 64 + c];
  }
  __syncthreads();

  const int lane = threadIdx.x & 63;
  const int bch = __builtin_amdgcn_readfirstlane((blockIdx.x << 2) + (threadIdx.x >> 6));
  const float4* fq = rkdc + (size_t)bch * (CL * CC);
  const float* vq = v_i + (size_t)bch * (CL * CC) + lane;
  const float* gq = g_i + (size_t)bch * (CL * CC) + lane;
  float* oq = out + (size_t)bch * (CL * CC) + lane;
  const float lnw = ln_w[lane], lnb = ln_b[lane];

  float S[CC];
  const float* si = S0 + (size_t)bch * (CC * CC) + lane;
#pragma unroll
  for (int i = 0; i < CC; ++i) S[i] = si[i * CC];

  for (int t = 0; t < CL; ++t) {
    const float4* ft = fq + t * CC;
    const float vv = vq[t * CC];
    float y0, y1;
    {
      const float4 f = ft[0];
      y0 = fmaf(f.x, S[0], f.w * vv);
      S[0] = fmaf(f.z, S[0], f.y * vv);
    }
    {
      const float4 f = ft[1];
      y1 = f.x * S[1];
      S[1] = fmaf(f.z, S[1], f.y * vv);
    }
#pragma unroll
    for (int i = 2; i < CC; i += 2) {
      const float4 fa = ft[i];
      y0 = fmaf(fa.x, S[i], y0);
      S[i] = fmaf(fa.z, S[i], fa.y * vv);
      const float4 fb = ft[i + 1];
      y1 = fmaf(fb.x, S[i + 1], y1);
      S[i + 1] = fmaf(fb.z, S[i + 1], fb.y * vv);
    }
    const float y = y0 + y1;

    const float s1 = wave_red_sum(y);
    const float s2 = wave_red_sum(y * y);
    const float mu = s1 * (1.f / CC);
    const float var = s2 * (1.f / CC) - mu * mu;
    const float z = (y - mu) * rsqrtf(var + GN_EPS) * lnw + lnb;
    const float sz = z * gq[t * CC];
    float acc = 0.f;
#pragma unroll
    for (int c = 0; c < CC; ++c) acc = fmaf(rl(sz, c), WoT[c * 64 + lane], acc);
    oq[t * CC] = acc;
  }
}

extern "C" void kernel_launch(void* const* d_in, const int* in_sizes, int n_in,
                              void* d_out, int out_size, void* d_ws, size_t ws_size,
                              hipStream_t stream) {
  const float* x       = (const float*)d_in[0];
  const float* tm_x    = (const float*)d_in[1];
  const float* tm_w    = (const float*)d_in[2];
  const float* tm_k    = (const float*)d_in[3];
  const float* tm_v    = (const float*)d_in[4];
  const float* tm_r    = (const float*)d_in[5];
  const float* tm_g    = (const float*)d_in[6];
  const float* maa_w1  = (const float*)d_in[7];
  const float* maa_w2  = (const float*)d_in[8];
  const float* t_decay = (const float*)d_in[9];
  const float* dec_w1  = (const float*)d_in[10];
  const float* dec_w2  = (const float*)d_in[11];
  const float* u       = (const float*)d_in[12];
  const float* Wr      = (const float*)d_in[13];
  const float* Wk      = (const float*)d_in[14];
  const float* Wv      = (const float*)d_in[15];
  const float* Wg      = (const float*)d_in[16];
  const float* Wo      = (const float*)d_in[17];
  const float* ln_w    = (const float*)d_in[18];
  const float* ln_b    = (const float*)d_in[19];

  const size_t M = (size_t)BT * CC;  // 4.19M floats
  float* ws   = (float*)d_ws;
  float* xk_o = ws;                  // [0,M)   dead after proj4
  float* xv_o = ws + M;              // [M,2M)  dead after proj4
  float* xr_o = ws + 2 * M;          // [2M,3M) dead after proj4
  float* xg_o = ws + 3 * M;          // [3M,4M) dead after proj4
  float* g_o  = ws + 4 * M;          // alive until scanC
  float* v_o  = ws + 5 * M;          // alive until scanC
  float* rkdc = ws + 6 * M;          // [6M,10M) float4 stream
  float* scb  = ws;                  // Sloc/S0 in place: BB*NCH*4096 = 16.8M floats [0,4M)
  float* w1T  = ws + 10 * M;         // 10240
  float* w2T  = w1T + 160 * 64;      // 10240
  float* d1T  = w2T + 5 * 64 * 32;   // 4096
  float* d2T  = d1T + 4096;          // 4096
  float* out  = (float*)d_out;
  float* Dp   = out;                 // BB*NCH*CC = 262144 floats scratch in d_out;
                                     // scanC fully overwrites out afterwards.

  preT_kernel<<<64, 256, 0, stream>>>(
      maa_w1, maa_w2, dec_w1, dec_w2, w1T, w2T, d1T, d2T);

  mix_mfma_kernel<<<BT / 128, 256, 0, stream>>>(
      x, tm_x, tm_w, tm_k, tm_v, tm_r, tm_g,
      w1T, w2T, d1T, d2T, t_decay,
      xk_o, xv_o, xr_o, xg_o, rkdc);

  proj4_mfma_kernel<<<BT / 128, 256, 0, stream>>>(
      xk_o, xv_o, xr_o, xg_o, u, Wr, Wk, Wv, Wg, rkdc, v_o, g_o);

  chunkA_kernel<<<(BB * NCH) / 4, 256, 0, stream>>>(
      (const float4*)rkdc, v_o, scb, Dp);

  combine_kernel<<<(BB * 4096) / 256, 256, 0, stream>>>(scb, Dp);

  scanC_kernel<<<(BB * NCH) / 4, 256, 0, stream>>>(
      (const float4*)rkdc, v_o, scb, g_o, ln_w, ln_b, Wo, out);
}

// Round 15
// 230.129 us; speedup vs baseline: 1.4990x; 1.4990x over previous
//
#include <hip/hip_runtime.h>

#define BB 32
#define TT 2048
#define CC 64
#define BT (BB * TT)
#define NCH 64
#define CL 32  // chunk length; NCH*CL == TT
#define GN_EPS (1e-5f * 64.f)

typedef short short8 __attribute__((ext_vector_type(8)));
typedef float f32x4 __attribute__((ext_vector_type(4)));

// ---- cross-lane helpers --------------------------------------------------
__device__ __forceinline__ float rl(float v, int lane) {
  return __uint_as_float(__builtin_amdgcn_readlane(__float_as_uint(v), lane));
}
template <int CTRL>
__device__ __forceinline__ float dppadd(float x) {
  return x + __int_as_float(__builtin_amdgcn_update_dpp(
                 0, __float_as_int(x), CTRL, 0xf, 0xf, true));
}
__device__ __forceinline__ float wave_red_sum(float x) {
  x = dppadd<0x111>(x);
  x = dppadd<0x112>(x);
  x = dppadd<0x114>(x);
  x = dppadd<0x118>(x);
  x = dppadd<0x142>(x);
  x = dppadd<0x143>(x);
  return __uint_as_float(__builtin_amdgcn_readlane(__float_as_uint(x), 63));
}
__device__ __forceinline__ float tanh_f(float x) {
  x = fminf(fmaxf(x, -10.f), 10.f);
  const float e = __expf(2.f * x);
  return (e - 1.f) / (e + 1.f);
}

// ---- bf16 helpers --------------------------------------------------------
__device__ __forceinline__ unsigned short f2bf(float x) {
  unsigned int u = __float_as_uint(x);
  u += 0x7FFFu + ((u >> 16) & 1u);   // RNE
  return (unsigned short)(u >> 16);
}
__device__ __forceinline__ float bf2f(unsigned short h) {
  return __uint_as_float(((unsigned int)h) << 16);
}
__device__ __forceinline__ short8 cvt8(const float4 a, const float4 b) {
  short8 h;
  h[0] = (short)f2bf(a.x); h[1] = (short)f2bf(a.y);
  h[2] = (short)f2bf(a.z); h[3] = (short)f2bf(a.w);
  h[4] = (short)f2bf(b.x); h[5] = (short)f2bf(b.y);
  h[6] = (short)f2bf(b.z); h[7] = (short)f2bf(b.w);
  return h;
}
__device__ __forceinline__ short8 ldb8(const float* __restrict__ p) {
  const float4 v0 = *reinterpret_cast<const float4*>(p);
  const float4 v1 = *reinterpret_cast<const float4*>(p + 4);
  return cvt8(v0, v1);
}
__device__ __forceinline__ short8 ldb8_lds(const float* p) {
  const float4 v0 = *reinterpret_cast<const float4*>(p);
  const float4 v1 = *reinterpret_cast<const float4*>(p + 4);
  return cvt8(v0, v1);
}

// ---- preT: transpose tiny weights for contiguous B-fragments -------------
__global__ __launch_bounds__(256) void preT_kernel(
    const float* __restrict__ maa_w1, const float* __restrict__ maa_w2,
    const float* __restrict__ dec_w1, const float* __restrict__ dec_w2,
    float* __restrict__ w1T, float* __restrict__ w2T,
    float* __restrict__ d1T, float* __restrict__ d2T)
{
  const int t0 = blockIdx.x * 256 + threadIdx.x;
  const int stride = gridDim.x * 256;
  for (int i = t0; i < 160 * 64; i += stride) {
    const int n = i >> 6, c = i & 63;
    w1T[i] = maa_w1[c * 160 + n];               // w1T[n][c]
  }
  for (int i = t0; i < 5 * 64 * 32; i += stride) {
    const int f = i >> 11, rem = i & 2047, n = rem >> 5, q = rem & 31;
    w2T[i] = maa_w2[(f * 32 + q) * 64 + n];     // w2T[f][n][q]
  }
  for (int i = t0; i < 4096; i += stride) {
    const int n = i >> 6, c = i & 63;
    d1T[i] = dec_w1[c * 64 + n];                // d1T[n][c]
    d2T[i] = dec_w2[c * 64 + n];                // d2T[n][q]
  }
}

// ---- mix via MFMA: token-shift + maa mixing + decay MLP ------------------
#define LDS_A 36
#define LDS_X 68
__global__ __launch_bounds__(256) void mix_mfma_kernel(
    const float* __restrict__ x,
    const float* __restrict__ tm_x, const float* __restrict__ tm_w, const float* __restrict__ tm_k,
    const float* __restrict__ tm_v, const float* __restrict__ tm_r, const float* __restrict__ tm_g,
    const float* __restrict__ w1T, const float* __restrict__ w2T,
    const float* __restrict__ d1T, const float* __restrict__ d2T,
    const float* __restrict__ t_decay,
    float* __restrict__ xk_o, float* __restrict__ xv_o,
    float* __restrict__ xr_o, float* __restrict__ xg_o,
    float* __restrict__ rkdc)
{
  __shared__ float aT[4][32][LDS_A];   // per-wave a-transpose (32x32 used)
  __shared__ float xT[4][32][LDS_X];   // per-wave xw / h transpose (32x64)
  const int lane = threadIdx.x & 63;
  const int wid = threadIdx.x >> 6;
  const int col = lane & 15, half = lane >> 4;
  const int tok0 = blockIdx.x * 128 + wid * 32;

  short8 xa[2][2];
#pragma unroll
  for (int m = 0; m < 2; ++m)
#pragma unroll
    for (int kk = 0; kk < 2; ++kk) {
      const int tok = tok0 + m * 16 + col;
      const int kb = kk * 32 + half * 8;
      const float* pc = x + (size_t)tok * CC + kb;
      const float4 c0 = *reinterpret_cast<const float4*>(pc);
      const float4 c1 = *reinterpret_cast<const float4*>(pc + 4);
      float4 p0 = {0.f, 0.f, 0.f, 0.f}, p1 = {0.f, 0.f, 0.f, 0.f};
      if ((tok & (TT - 1)) != 0) {
        p0 = *reinterpret_cast<const float4*>(pc - CC);
        p1 = *reinterpret_cast<const float4*>(pc - CC + 4);
      }
      const float4 t0 = *reinterpret_cast<const float4*>(tm_x + kb);
      const float4 t1 = *reinterpret_cast<const float4*>(tm_x + kb + 4);
      const float cv[8] = {c0.x, c0.y, c0.z, c0.w, c1.x, c1.y, c1.z, c1.w};
      const float pv[8] = {p0.x, p0.y, p0.z, p0.w, p1.x, p1.y, p1.z, p1.w};
      const float tv[8] = {t0.x, t0.y, t0.z, t0.w, t1.x, t1.y, t1.z, t1.w};
      short8 h;
#pragma unroll
      for (int e = 0; e < 8; ++e)
        h[e] = (short)f2bf(fmaf(pv[e] - cv[e], tv[e], cv[e]));
      xa[m][kk] = h;
    }

  float xcv[2][4][4], xxv[2][4][4];
#pragma unroll
  for (int m = 0; m < 2; ++m)
#pragma unroll
    for (int reg = 0; reg < 4; ++reg) {
      const int tok = tok0 + m * 16 + half * 4 + reg;
      const bool has = (tok & (TT - 1)) != 0;
#pragma unroll
      for (int nt = 0; nt < 4; ++nt) {
        const size_t o = (size_t)tok * CC + nt * 16 + col;
        const float cur = x[o];
        const float prv = has ? x[o - CC] : 0.f;
        xcv[m][nt][reg] = cur;
        xxv[m][nt][reg] = prv - cur;
      }
    }

  auto process_f = [&](int f, const float* __restrict__ tmf,
                       float* __restrict__ gout) {
    f32x4 acc1[2][2];
#pragma unroll
    for (int m = 0; m < 2; ++m)
#pragma unroll
      for (int ntf = 0; ntf < 2; ++ntf) acc1[m][ntf] = (f32x4){0.f, 0.f, 0.f, 0.f};
    short8 b1[2][2];
#pragma unroll
    for (int ntf = 0; ntf < 2; ++ntf)
#pragma unroll
      for (int kk = 0; kk < 2; ++kk)
        b1[ntf][kk] = ldb8(w1T + (size_t)(f * 32 + ntf * 16 + col) * 64 + kk * 32 + half * 8);
#pragma unroll
    for (int m = 0; m < 2; ++m)
#pragma unroll
      for (int ntf = 0; ntf < 2; ++ntf)
#pragma unroll
        for (int kk = 0; kk < 2; ++kk)
          acc1[m][ntf] = __builtin_amdgcn_mfma_f32_16x16x32_bf16(
              xa[m][kk], b1[ntf][kk], acc1[m][ntf], 0, 0, 0);
#pragma unroll
    for (int m = 0; m < 2; ++m)
#pragma unroll
      for (int ntf = 0; ntf < 2; ++ntf)
#pragma unroll
        for (int reg = 0; reg < 4; ++reg)
          aT[wid][m * 16 + half * 4 + reg][ntf * 16 + col] = tanh_f(acc1[m][ntf][reg]);
    short8 a2[2];
#pragma unroll
    for (int m = 0; m < 2; ++m)
      a2[m] = ldb8_lds(&aT[wid][m * 16 + col][half * 8]);
    f32x4 acc2[2][4];
#pragma unroll
    for (int m = 0; m < 2; ++m)
#pragma unroll
      for (int nt = 0; nt < 4; ++nt) acc2[m][nt] = (f32x4){0.f, 0.f, 0.f, 0.f};
    short8 b2[4];
#pragma unroll
    for (int nt = 0; nt < 4; ++nt)
      b2[nt] = ldb8(w2T + (size_t)f * 2048 + (nt * 16 + col) * 32 + half * 8);
#pragma unroll
    for (int m = 0; m < 2; ++m)
#pragma unroll
      for (int nt = 0; nt < 4; ++nt)
        acc2[m][nt] = __builtin_amdgcn_mfma_f32_16x16x32_bf16(
            a2[m], b2[nt], acc2[m][nt], 0, 0, 0);
    float tmf4[4];
#pragma unroll
    for (int nt = 0; nt < 4; ++nt) tmf4[nt] = tmf[nt * 16 + col];
#pragma unroll
    for (int m = 0; m < 2; ++m)
#pragma unroll
      for (int nt = 0; nt < 4; ++nt)
#pragma unroll
        for (int reg = 0; reg < 4; ++reg) {
          const float val = fmaf(xxv[m][nt][reg], tmf4[nt] + acc2[m][nt][reg],
                                 xcv[m][nt][reg]);
          if (gout)
            gout[(size_t)(tok0 + m * 16 + half * 4 + reg) * CC + nt * 16 + col] = val;
          else
            xT[wid][m * 16 + half * 4 + reg][nt * 16 + col] = val;
        }
  };

  process_f(1, tm_k, xk_o);
  process_f(2, tm_v, xv_o);
  process_f(3, tm_r, xr_o);
  process_f(4, tm_g, xg_o);
  process_f(0, tm_w, nullptr);   // xw -> LDS xT

  short8 xwf[2][2];
#pragma unroll
  for (int m = 0; m < 2; ++m)
#pragma unroll
    for (int kk = 0; kk < 2; ++kk)
      xwf[m][kk] = ldb8_lds(&xT[wid][m * 16 + col][kk * 32 + half * 8]);
  f32x4 hcc[2][4];
#pragma unroll
  for (int m = 0; m < 2; ++m)
#pragma unroll
    for (int nt = 0; nt < 4; ++nt) hcc[m][nt] = (f32x4){0.f, 0.f, 0.f, 0.f};
  short8 bd[4][2];
#pragma unroll
  for (int nt = 0; nt < 4; ++nt)
#pragma unroll
    for (int kk = 0; kk < 2; ++kk)
      bd[nt][kk] = ldb8(d1T + (size_t)(nt * 16 + col) * 64 + kk * 32 + half * 8);
#pragma unroll
  for (int m = 0; m < 2; ++m)
#pragma unroll
    for (int nt = 0; nt < 4; ++nt)
#pragma unroll
      for (int kk = 0; kk < 2; ++kk)
        hcc[m][nt] = __builtin_amdgcn_mfma_f32_16x16x32_bf16(
            xwf[m][kk], bd[nt][kk], hcc[m][nt], 0, 0, 0);
#pragma unroll
  for (int m = 0; m < 2; ++m)
#pragma unroll
    for (int nt = 0; nt < 4; ++nt)
#pragma unroll
      for (int reg = 0; reg < 4; ++reg)
        xT[wid][m * 16 + half * 4 + reg][nt * 16 + col] = tanh_f(hcc[m][nt][reg]);
  short8 hf[2][2];
#pragma unroll
  for (int m = 0; m < 2; ++m)
#pragma unroll
    for (int kk = 0; kk < 2; ++kk)
      hf[m][kk] = ldb8_lds(&xT[wid][m * 16 + col][kk * 32 + half * 8]);
  f32x4 wfa[2][4];
#pragma unroll
  for (int m = 0; m < 2; ++m)
#pragma unroll
    for (int nt = 0; nt < 4; ++nt) wfa[m][nt] = (f32x4){0.f, 0.f, 0.f, 0.f};
#pragma unroll
  for (int nt = 0; nt < 4; ++nt)
#pragma unroll
    for (int kk = 0; kk < 2; ++kk)
      bd[nt][kk] = ldb8(d2T + (size_t)(nt * 16 + col) * 64 + kk * 32 + half * 8);
#pragma unroll
  for (int m = 0; m < 2; ++m)
#pragma unroll
    for (int nt = 0; nt < 4; ++nt)
#pragma unroll
      for (int kk = 0; kk < 2; ++kk)
        wfa[m][nt] = __builtin_amdgcn_mfma_f32_16x16x32_bf16(
            hf[m][kk], bd[nt][kk], wfa[m][nt], 0, 0, 0);
  float td4[4];
#pragma unroll
  for (int nt = 0; nt < 4; ++nt) td4[nt] = t_decay[nt * 16 + col];
#pragma unroll
  for (int m = 0; m < 2; ++m)
#pragma unroll
    for (int nt = 0; nt < 4; ++nt)
#pragma unroll
      for (int reg = 0; reg < 4; ++reg)
        rkdc[4 * ((size_t)(tok0 + m * 16 + half * 4 + reg) * CC + nt * 16 + col) + 2] =
            __expf(-__expf(wfa[m][nt][reg] + td4[nt]));
}

// ---- proj4 via MFMA (bf16 3-product split) -------------------------------
__device__ __forceinline__ void load_afrag(
    const float* __restrict__ X, int tok0, int col, int half,
    short8 ah[2][2], short8 al[2][2])
{
#pragma unroll
  for (int m = 0; m < 2; ++m)
#pragma unroll
    for (int kk = 0; kk < 2; ++kk) {
      const float* p = X + (size_t)(tok0 + m * 16 + col) * CC + kk * 32 + half * 8;
      const float4 v0 = *reinterpret_cast<const float4*>(p);
      const float4 v1 = *reinterpret_cast<const float4*>(p + 4);
      const float vv[8] = {v0.x, v0.y, v0.z, v0.w, v1.x, v1.y, v1.z, v1.w};
      short8 h, l;
#pragma unroll
      for (int e = 0; e < 8; ++e) {
        const unsigned short hb = f2bf(vv[e]);
        h[e] = (short)hb;
        l[e] = (short)f2bf(vv[e] - bf2f(hb));
      }
      ah[m][kk] = h; al[m][kk] = l;
    }
}
__device__ __forceinline__ void load_bfrag(
    const float* __restrict__ W, int col, int half,
    short8 bh[4][2], short8 bl[4][2])
{
#pragma unroll
  for (int n = 0; n < 4; ++n)
#pragma unroll
    for (int kk = 0; kk < 2; ++kk) {
      const float* p = W + (size_t)(n * 16 + col) * CC + kk * 32 + half * 8;
      const float4 v0 = *reinterpret_cast<const float4*>(p);
      const float4 v1 = *reinterpret_cast<const float4*>(p + 4);
      const float vv[8] = {v0.x, v0.y, v0.z, v0.w, v1.x, v1.y, v1.z, v1.w};
      short8 h, l;
#pragma unroll
      for (int e = 0; e < 8; ++e) {
        const unsigned short hb = f2bf(vv[e]);
        h[e] = (short)hb;
        l[e] = (short)f2bf(vv[e] - bf2f(hb));
      }
      bh[n][kk] = h; bl[n][kk] = l;
    }
}
__device__ __forceinline__ void gemm_acc(
    const short8 ah[2][2], const short8 al[2][2],
    const short8 bh[4][2], const short8 bl[4][2], f32x4 acc[2][4])
{
#pragma unroll
  for (int m = 0; m < 2; ++m)
#pragma unroll
    for (int n = 0; n < 4; ++n) {
      f32x4 a = acc[m][n];
#pragma unroll
      for (int kk = 0; kk < 2; ++kk) {
        a = __builtin_amdgcn_mfma_f32_16x16x32_bf16(ah[m][kk], bh[n][kk], a, 0, 0, 0);
        a = __builtin_amdgcn_mfma_f32_16x16x32_bf16(ah[m][kk], bl[n][kk], a, 0, 0, 0);
        a = __builtin_amdgcn_mfma_f32_16x16x32_bf16(al[m][kk], bh[n][kk], a, 0, 0, 0);
      }
      acc[m][n] = a;
    }
}

__global__ __launch_bounds__(256) void proj4_mfma_kernel(
    const float* __restrict__ xk_i, const float* __restrict__ xv_i,
    const float* __restrict__ xr_i, const float* __restrict__ xg_i,
    const float* __restrict__ u,
    const float* __restrict__ Wr, const float* __restrict__ Wk, const float* __restrict__ Wv,
    const float* __restrict__ Wg,
    float* __restrict__ rkdc, float* __restrict__ v_o, float* __restrict__ g_o)
{
  const int lane = threadIdx.x & 63;
  const int wid = threadIdx.x >> 6;
  const int col = lane & 15, half = lane >> 4;
  const int tok0 = blockIdx.x * 128 + wid * 32;

  short8 ah[2][2], al[2][2], bh[4][2], bl[4][2];
  f32x4 accr[2][4], acck[2][4];

  load_bfrag(Wr, col, half, bh, bl);
  load_afrag(xr_i, tok0, col, half, ah, al);
#pragma unroll
  for (int m = 0; m < 2; ++m)
#pragma unroll
    for (int n = 0; n < 4; ++n) accr[m][n] = (f32x4){0.f, 0.f, 0.f, 0.f};
  gemm_acc(ah, al, bh, bl, accr);

  load_bfrag(Wk, col, half, bh, bl);
  load_afrag(xk_i, tok0, col, half, ah, al);
#pragma unroll
  for (int m = 0; m < 2; ++m)
#pragma unroll
    for (int n = 0; n < 4; ++n) acck[m][n] = (f32x4){0.f, 0.f, 0.f, 0.f};
  gemm_acc(ah, al, bh, bl, acck);

  float uv[4];
#pragma unroll
  for (int n = 0; n < 4; ++n) uv[n] = u[n * 16 + col];
  float ctv[2][4];
#pragma unroll
  for (int m = 0; m < 2; ++m)
#pragma unroll
    for (int reg = 0; reg < 4; ++reg) {
      float p = 0.f;
#pragma unroll
      for (int n = 0; n < 4; ++n)
        p += accr[m][n][reg] * uv[n] * acck[m][n][reg];
      p += __shfl_xor(p, 1, 64);
      p += __shfl_xor(p, 2, 64);
      p += __shfl_xor(p, 4, 64);
      p += __shfl_xor(p, 8, 64);
      ctv[m][reg] = p;
    }

#pragma unroll
  for (int m = 0; m < 2; ++m)
#pragma unroll
    for (int n = 0; n < 4; ++n)
#pragma unroll
      for (int reg = 0; reg < 4; ++reg) {
        const int token = tok0 + m * 16 + half * 4 + reg;
        const size_t o = (size_t)token * CC + n * 16 + col;
        rkdc[4 * o + 0] = accr[m][n][reg];
        rkdc[4 * o + 1] = acck[m][n][reg];
        rkdc[4 * o + 3] = ctv[m][reg];
      }

  load_bfrag(Wv, col, half, bh, bl);
  load_afrag(xv_i, tok0, col, half, ah, al);
#pragma unroll
  for (int m = 0; m < 2; ++m)
#pragma unroll
    for (int n = 0; n < 4; ++n) accr[m][n] = (f32x4){0.f, 0.f, 0.f, 0.f};
  gemm_acc(ah, al, bh, bl, accr);
#pragma unroll
  for (int m = 0; m < 2; ++m)
#pragma unroll
    for (int n = 0; n < 4; ++n)
#pragma unroll
      for (int reg = 0; reg < 4; ++reg) {
        const int token = tok0 + m * 16 + half * 4 + reg;
        v_o[(size_t)token * CC + n * 16 + col] = accr[m][n][reg];
      }

  load_bfrag(Wg, col, half, bh, bl);
  load_afrag(xg_i, tok0, col, half, ah, al);
#pragma unroll
  for (int m = 0; m < 2; ++m)
#pragma unroll
    for (int n = 0; n < 4; ++n) accr[m][n] = (f32x4){0.f, 0.f, 0.f, 0.f};
  gemm_acc(ah, al, bh, bl, accr);
#pragma unroll
  for (int m = 0; m < 2; ++m)
#pragma unroll
    for (int n = 0; n < 4; ++n)
#pragma unroll
      for (int reg = 0; reg < 4; ++reg) {
        const int token = tok0 + m * 16 + half * 4 + reg;
        const float gg = accr[m][n][reg];
        g_o[(size_t)token * CC + n * 16 + col] = gg / (1.f + __expf(-gg));
      }
}

// ---- A: chunk-local state. Wave = (b,ch); lane = i now. ------------------
// Per-lane coalesced float4 rkdc loads (k,d are lane-local); v broadcast
// via readlane. Writes SlocT[j][i] (transposed) + Dp[i] (lane-local dp).
__global__ __launch_bounds__(256) void chunkA_kernel(
    const float4* __restrict__ rkdc, const float* __restrict__ v_i,
    float* __restrict__ SlocT, float* __restrict__ Dp)
{
  const int lane = threadIdx.x & 63;   // i
  const int bch = __builtin_amdgcn_readfirstlane((blockIdx.x << 2) + (threadIdx.x >> 6));
  const float4* fq = rkdc + (size_t)bch * (CL * CC) + lane;
  const float* vq = v_i + (size_t)bch * (CL * CC) + lane;

  float S[CC];
#pragma unroll
  for (int j = 0; j < CC; ++j) S[j] = 0.f;
  float dp = 1.f;

  for (int t = 0; t < CL; ++t) {
    const float4 f = fq[t * CC];       // (t, i=lane): k=f.y, d=f.z, coalesced
    const float vf = vq[t * CC];       // v[t][lane], coalesced
    dp *= f.z;
#pragma unroll
    for (int j = 0; j < CC; ++j) {
      const float vj = rl(vf, j);      // broadcast v[t][j]
      S[j] = fmaf(f.z, S[j], f.y * vj);
    }
  }
  // SlocT[j][i]: lane=i writes column i of each row j -> coalesced per j.
  float* so = SlocT + (size_t)bch * (CC * CC) + lane;
#pragma unroll
  for (int j = 0; j < CC; ++j) so[j * CC] = S[j];
  Dp[(size_t)bch * CC + lane] = dp;
}

// ---- B: in-place combine over chunks (transposed [j][i] layout) ----------
__global__ __launch_bounds__(1024) void combine_kernel(
    float* __restrict__ buf, const float* __restrict__ Dp)
{
  const int b = blockIdx.x, tid = threadIdx.x;
  __shared__ float sDp[NCH * CC];
  for (int idx = tid; idx < NCH * CC; idx += 1024)
    sDp[idx] = Dp[(size_t)b * NCH * CC + idx];
  __syncthreads();
  float run[4] = {0.f, 0.f, 0.f, 0.f};
  for (int ch = 0; ch < NCH; ++ch) {
    const size_t base = ((size_t)(b * NCH + ch)) * (CC * CC);
    const float* drow = sDp + ch * CC;
#pragma unroll
    for (int k2 = 0; k2 < 4; ++k2) {
      const int idx = tid + (k2 << 10);
      const float tmp = buf[base + idx];
      buf[base + idx] = run[k2];
      run[k2] = fmaf(run[k2], drow[idx & 63], tmp);   // decay channel i = idx&63
    }
  }
}

// ---- C: emit + GroupNorm + *g + @Wo.T fused ------------------------------
// rkdc row loaded per-lane (coalesced float4) + readlane broadcast; S0T row
// loaded as 16 coalesced float4 per lane; 4-way parallel Wo accumulators.
__global__ __launch_bounds__(256) void scanC_kernel(
    const float4* __restrict__ rkdc, const float* __restrict__ v_i,
    const float* __restrict__ S0T, const float* __restrict__ g_i,
    const float* __restrict__ ln_w, const float* __restrict__ ln_b,
    const float* __restrict__ Wo, float* __restrict__ out)
{
  __shared__ float WoT[4096];
  for (int idx = threadIdx.x; idx < 4096; idx += 256) {
    const int c = idx >> 6, jj = idx & 63;
    WoT[idx] = Wo[jj * 64 + c];
  }
  __syncthreads();

  const int lane = threadIdx.x & 63;   // j (and i for the rkdc load role)
  const int bch = __builtin_amdgcn_readfirstlane((blockIdx.x << 2) + (threadIdx.x >> 6));
  const float4* fq = rkdc + (size_t)bch * (CL * CC) + lane;
  const float* vq = v_i + (size_t)bch * (CL * CC) + lane;
  const float* gq = g_i + (size_t)bch * (CL * CC) + lane;
  float* oq = out + (size_t)bch * (CL * CC) + lane;
  const float lnw = ln_w[lane], lnb = ln_b[lane];

  float S[CC];
  const float* si = S0T + (size_t)bch * (CC * CC) + (size_t)lane * CC;  // row j
#pragma unroll
  for (int i4 = 0; i4 < 16; ++i4) {
    const float4 s4 = *reinterpret_cast<const float4*>(si + i4 * 4);
    S[i4 * 4 + 0] = s4.x; S[i4 * 4 + 1] = s4.y;
    S[i4 * 4 + 2] = s4.z; S[i4 * 4 + 3] = s4.w;
  }

  for (int t = 0; t < CL; ++t) {
    const float4 f = fq[t * CC];   // lane's own (t, i=lane) cell; f.w = ct[t]
    const float vv = vq[t * CC];
    float y0 = f.w * vv, y1 = 0.f, y2 = 0.f, y3 = 0.f;
#pragma unroll
    for (int i = 0; i < CC; i += 4) {
      const float r0 = rl(f.x, i),     k0 = rl(f.y, i),     d0 = rl(f.z, i);
      y0 = fmaf(r0, S[i], y0);     S[i]     = fmaf(d0, S[i],     k0 * vv);
      const float r1 = rl(f.x, i + 1), k1 = rl(f.y, i + 1), d1 = rl(f.z, i + 1);
      y1 = fmaf(r1, S[i + 1], y1); S[i + 1] = fmaf(d1, S[i + 1], k1 * vv);
      const float r2 = rl(f.x, i + 2), k2 = rl(f.y, i + 2), d2 = rl(f.z, i + 2);
      y2 = fmaf(r2, S[i + 2], y2); S[i + 2] = fmaf(d2, S[i + 2], k2 * vv);
      const float r3 = rl(f.x, i + 3), k3 = rl(f.y, i + 3), d3 = rl(f.z, i + 3);
      y3 = fmaf(r3, S[i + 3], y3); S[i + 3] = fmaf(d3, S[i + 3], k3 * vv);
    }
    const float y = (y0 + y1) + (y2 + y3);

    const float s1 = wave_red_sum(y);
    const float s2 = wave_red_sum(y * y);
    const float mu = s1 * (1.f / CC);
    const float var = s2 * (1.f / CC) - mu * mu;
    const float z = (y - mu) * rsqrtf(var + GN_EPS) * lnw + lnb;
    const float sz = z * gq[t * CC];
    float a0 = 0.f, a1 = 0.f, a2 = 0.f, a3 = 0.f;
#pragma unroll
    for (int c = 0; c < CC; c += 4) {
      a0 = fmaf(rl(sz, c),     WoT[c * 64 + lane],       a0);
      a1 = fmaf(rl(sz, c + 1), WoT[(c + 1) * 64 + lane], a1);
      a2 = fmaf(rl(sz, c + 2), WoT[(c + 2) * 64 + lane], a2);
      a3 = fmaf(rl(sz, c + 3), WoT[(c + 3) * 64 + lane], a3);
    }
    oq[t * CC] = (a0 + a1) + (a2 + a3);
  }
}

extern "C" void kernel_launch(void* const* d_in, const int* in_sizes, int n_in,
                              void* d_out, int out_size, void* d_ws, size_t ws_size,
                              hipStream_t stream) {
  const float* x       = (const float*)d_in[0];
  const float* tm_x    = (const float*)d_in[1];
  const float* tm_w    = (const float*)d_in[2];
  const float* tm_k    = (const float*)d_in[3];
  const float* tm_v    = (const float*)d_in[4];
  const float* tm_r    = (const float*)d_in[5];
  const float* tm_g    = (const float*)d_in[6];
  const float* maa_w1  = (const float*)d_in[7];
  const float* maa_w2  = (const float*)d_in[8];
  const float* t_decay = (const float*)d_in[9];
  const float* dec_w1  = (const float*)d_in[10];
  const float* dec_w2  = (const float*)d_in[11];
  const float* u       = (const float*)d_in[12];
  const float* Wr      = (const float*)d_in[13];
  const float* Wk      = (const float*)d_in[14];
  const float* Wv      = (const float*)d_in[15];
  const float* Wg      = (const float*)d_in[16];
  const float* Wo      = (const float*)d_in[17];
  const float* ln_w    = (const float*)d_in[18];
  const float* ln_b    = (const float*)d_in[19];

  const size_t M = (size_t)BT * CC;  // 4.19M floats
  float* ws   = (float*)d_ws;
  float* xk_o = ws;                  // [0,M)   dead after proj4
  float* xv_o = ws + M;              // [M,2M)  dead after proj4
  float* xr_o = ws + 2 * M;          // [2M,3M) dead after proj4
  float* xg_o = ws + 3 * M;          // [3M,4M) dead after proj4
  float* g_o  = ws + 4 * M;          // alive until scanC
  float* v_o  = ws + 5 * M;          // alive until scanC
  float* rkdc = ws + 6 * M;          // [6M,10M) float4 stream
  float* scb  = ws;                  // SlocT==S0T (in-place), 2M floats
  float* Dp   = ws + 2 * M;          // aliases dead xr_o
  float* w1T  = ws + 10 * M;         // 10240
  float* w2T  = w1T + 160 * 64;      // 10240
  float* d1T  = w2T + 5 * 64 * 32;   // 4096
  float* d2T  = d1T + 4096;          // 4096
  float* out  = (float*)d_out;

  preT_kernel<<<64, 256, 0, stream>>>(
      maa_w1, maa_w2, dec_w1, dec_w2, w1T, w2T, d1T, d2T);

  mix_mfma_kernel<<<BT / 128, 256, 0, stream>>>(
      x, tm_x, tm_w, tm_k, tm_v, tm_r, tm_g,
      w1T, w2T, d1T, d2T, t_decay,
      xk_o, xv_o, xr_o, xg_o, rkdc);

  proj4_mfma_kernel<<<BT / 128, 256, 0, stream>>>(
      xk_o, xv_o, xr_o, xg_o, u, Wr, Wk, Wv, Wg, rkdc, v_o, g_o);

  chunkA_kernel<<<(BB * NCH) / 4, 256, 0, stream>>>(
      (const float4*)rkdc, v_o, scb, Dp);

  combine_kernel<<<BB, 1024, 0, stream>>>(scb, Dp);

  scanC_kernel<<<(BB * NCH) / 4, 256, 0, stream>>>(
      (const float4*)rkdc, v_o, scb, g_o, ln_w, ln_b, Wo, out);
}

// Round 16
// 195.217 us; speedup vs baseline: 1.7670x; 1.1788x over previous
//
#include <hip/hip_runtime.h>

#define BB 32
#define TT 2048
#define CC 64
#define BT (BB * TT)
#define NCH 64
#define CL 32  // chunk length; NCH*CL == TT
#define GN_EPS (1e-5f * 64.f)
#define SW 36  // vT / k~T LDS stride (36*4=144, 16B-aligned rows)
#define SA 68  // [t][i]-style LDS stride (68*4=272, 16B-aligned rows)

typedef short short8 __attribute__((ext_vector_type(8)));
typedef float f32x4 __attribute__((ext_vector_type(4)));

// ---- cross-lane helpers --------------------------------------------------
__device__ __forceinline__ float rl(float v, int lane) {
  return __uint_as_float(__builtin_amdgcn_readlane(__float_as_uint(v), lane));
}
__device__ __forceinline__ float tanh_f(float x) {
  x = fminf(fmaxf(x, -10.f), 10.f);
  const float e = __expf(2.f * x);
  return (e - 1.f) / (e + 1.f);
}

// ---- bf16 helpers --------------------------------------------------------
__device__ __forceinline__ unsigned short f2bf(float x) {
  unsigned int u = __float_as_uint(x);
  u += 0x7FFFu + ((u >> 16) & 1u);   // RNE
  return (unsigned short)(u >> 16);
}
__device__ __forceinline__ float bf2f(unsigned short h) {
  return __uint_as_float(((unsigned int)h) << 16);
}
__device__ __forceinline__ short8 cvt8(const float4 a, const float4 b) {
  short8 h;
  h[0] = (short)f2bf(a.x); h[1] = (short)f2bf(a.y);
  h[2] = (short)f2bf(a.z); h[3] = (short)f2bf(a.w);
  h[4] = (short)f2bf(b.x); h[5] = (short)f2bf(b.y);
  h[6] = (short)f2bf(b.z); h[7] = (short)f2bf(b.w);
  return h;
}
__device__ __forceinline__ short8 ldb8(const float* __restrict__ p) {
  const float4 v0 = *reinterpret_cast<const float4*>(p);
  const float4 v1 = *reinterpret_cast<const float4*>(p + 4);
  return cvt8(v0, v1);
}
__device__ __forceinline__ short8 ldb8_lds(const float* p) {
  const float4 v0 = *reinterpret_cast<const float4*>(p);
  const float4 v1 = *reinterpret_cast<const float4*>(p + 4);
  return cvt8(v0, v1);
}
// fp32 -> (hi, lo) bf16 split load (8 elems)
__device__ __forceinline__ void splitload(const float* p, short8& h8, short8& l8) {
  const float4 v0 = *reinterpret_cast<const float4*>(p);
  const float4 v1 = *reinterpret_cast<const float4*>(p + 4);
  const float vv[8] = {v0.x, v0.y, v0.z, v0.w, v1.x, v1.y, v1.z, v1.w};
#pragma unroll
  for (int e = 0; e < 8; ++e) {
    const unsigned short hb = f2bf(vv[e]);
    h8[e] = (short)hb;
    l8[e] = (short)f2bf(vv[e] - bf2f(hb));
  }
}
__device__ __forceinline__ f32x4 mfma3(short8 ah, short8 al, short8 bh, short8 bl, f32x4 a) {
  a = __builtin_amdgcn_mfma_f32_16x16x32_bf16(ah, bh, a, 0, 0, 0);
  a = __builtin_amdgcn_mfma_f32_16x16x32_bf16(ah, bl, a, 0, 0, 0);
  a = __builtin_amdgcn_mfma_f32_16x16x32_bf16(al, bh, a, 0, 0, 0);
  return a;
}

// ---- preT: transpose tiny weights for contiguous B-fragments -------------
__global__ __launch_bounds__(256) void preT_kernel(
    const float* __restrict__ maa_w1, const float* __restrict__ maa_w2,
    const float* __restrict__ dec_w1, const float* __restrict__ dec_w2,
    float* __restrict__ w1T, float* __restrict__ w2T,
    float* __restrict__ d1T, float* __restrict__ d2T)
{
  const int t0 = blockIdx.x * 256 + threadIdx.x;
  const int stride = gridDim.x * 256;
  for (int i = t0; i < 160 * 64; i += stride) {
    const int n = i >> 6, c = i & 63;
    w1T[i] = maa_w1[c * 160 + n];
  }
  for (int i = t0; i < 5 * 64 * 32; i += stride) {
    const int f = i >> 11, rem = i & 2047, n = rem >> 5, q = rem & 31;
    w2T[i] = maa_w2[(f * 32 + q) * 64 + n];
  }
  for (int i = t0; i < 4096; i += stride) {
    const int n = i >> 6, c = i & 63;
    d1T[i] = dec_w1[c * 64 + n];
    d2T[i] = dec_w2[c * 64 + n];
  }
}

// ---- mix via MFMA (rkdc.z now holds ew = exp(w), not d) ------------------
#define LDS_A 36
#define LDS_X 68
__global__ __launch_bounds__(256) void mix_mfma_kernel(
    const float* __restrict__ x,
    const float* __restrict__ tm_x, const float* __restrict__ tm_w, const float* __restrict__ tm_k,
    const float* __restrict__ tm_v, const float* __restrict__ tm_r, const float* __restrict__ tm_g,
    const float* __restrict__ w1T, const float* __restrict__ w2T,
    const float* __restrict__ d1T, const float* __restrict__ d2T,
    const float* __restrict__ t_decay,
    float* __restrict__ xk_o, float* __restrict__ xv_o,
    float* __restrict__ xr_o, float* __restrict__ xg_o,
    float* __restrict__ rkdc)
{
  __shared__ float aT[4][32][LDS_A];
  __shared__ float xT[4][32][LDS_X];
  const int lane = threadIdx.x & 63;
  const int wid = threadIdx.x >> 6;
  const int col = lane & 15, half = lane >> 4;
  const int tok0 = blockIdx.x * 128 + wid * 32;

  short8 xa[2][2];
#pragma unroll
  for (int m = 0; m < 2; ++m)
#pragma unroll
    for (int kk = 0; kk < 2; ++kk) {
      const int tok = tok0 + m * 16 + col;
      const int kb = kk * 32 + half * 8;
      const float* pc = x + (size_t)tok * CC + kb;
      const float4 c0 = *reinterpret_cast<const float4*>(pc);
      const float4 c1 = *reinterpret_cast<const float4*>(pc + 4);
      float4 p0 = {0.f, 0.f, 0.f, 0.f}, p1 = {0.f, 0.f, 0.f, 0.f};
      if ((tok & (TT - 1)) != 0) {
        p0 = *reinterpret_cast<const float4*>(pc - CC);
        p1 = *reinterpret_cast<const float4*>(pc - CC + 4);
      }
      const float4 t0 = *reinterpret_cast<const float4*>(tm_x + kb);
      const float4 t1 = *reinterpret_cast<const float4*>(tm_x + kb + 4);
      const float cv[8] = {c0.x, c0.y, c0.z, c0.w, c1.x, c1.y, c1.z, c1.w};
      const float pv[8] = {p0.x, p0.y, p0.z, p0.w, p1.x, p1.y, p1.z, p1.w};
      const float tv[8] = {t0.x, t0.y, t0.z, t0.w, t1.x, t1.y, t1.z, t1.w};
      short8 h;
#pragma unroll
      for (int e = 0; e < 8; ++e)
        h[e] = (short)f2bf(fmaf(pv[e] - cv[e], tv[e], cv[e]));
      xa[m][kk] = h;
    }

  float xcv[2][4][4], xxv[2][4][4];
#pragma unroll
  for (int m = 0; m < 2; ++m)
#pragma unroll
    for (int reg = 0; reg < 4; ++reg) {
      const int tok = tok0 + m * 16 + half * 4 + reg;
      const bool has = (tok & (TT - 1)) != 0;
#pragma unroll
      for (int nt = 0; nt < 4; ++nt) {
        const size_t o = (size_t)tok * CC + nt * 16 + col;
        const float cur = x[o];
        const float prv = has ? x[o - CC] : 0.f;
        xcv[m][nt][reg] = cur;
        xxv[m][nt][reg] = prv - cur;
      }
    }

  auto process_f = [&](int f, const float* __restrict__ tmf,
                       float* __restrict__ gout) {
    f32x4 acc1[2][2];
#pragma unroll
    for (int m = 0; m < 2; ++m)
#pragma unroll
      for (int ntf = 0; ntf < 2; ++ntf) acc1[m][ntf] = (f32x4){0.f, 0.f, 0.f, 0.f};
    short8 b1[2][2];
#pragma unroll
    for (int ntf = 0; ntf < 2; ++ntf)
#pragma unroll
      for (int kk = 0; kk < 2; ++kk)
        b1[ntf][kk] = ldb8(w1T + (size_t)(f * 32 + ntf * 16 + col) * 64 + kk * 32 + half * 8);
#pragma unroll
    for (int m = 0; m < 2; ++m)
#pragma unroll
      for (int ntf = 0; ntf < 2; ++ntf)
#pragma unroll
        for (int kk = 0; kk < 2; ++kk)
          acc1[m][ntf] = __builtin_amdgcn_mfma_f32_16x16x32_bf16(
              xa[m][kk], b1[ntf][kk], acc1[m][ntf], 0, 0, 0);
#pragma unroll
    for (int m = 0; m < 2; ++m)
#pragma unroll
      for (int ntf = 0; ntf < 2; ++ntf)
#pragma unroll
        for (int reg = 0; reg < 4; ++reg)
          aT[wid][m * 16 + half * 4 + reg][ntf * 16 + col] = tanh_f(acc1[m][ntf][reg]);
    short8 a2[2];
#pragma unroll
    for (int m = 0; m < 2; ++m)
      a2[m] = ldb8_lds(&aT[wid][m * 16 + col][half * 8]);
    f32x4 acc2[2][4];
#pragma unroll
    for (int m = 0; m < 2; ++m)
#pragma unroll
      for (int nt = 0; nt < 4; ++nt) acc2[m][nt] = (f32x4){0.f, 0.f, 0.f, 0.f};
    short8 b2[4];
#pragma unroll
    for (int nt = 0; nt < 4; ++nt)
      b2[nt] = ldb8(w2T + (size_t)f * 2048 + (nt * 16 + col) * 32 + half * 8);
#pragma unroll
    for (int m = 0; m < 2; ++m)
#pragma unroll
      for (int nt = 0; nt < 4; ++nt)
        acc2[m][nt] = __builtin_amdgcn_mfma_f32_16x16x32_bf16(
            a2[m], b2[nt], acc2[m][nt], 0, 0, 0);
    float tmf4[4];
#pragma unroll
    for (int nt = 0; nt < 4; ++nt) tmf4[nt] = tmf[nt * 16 + col];
#pragma unroll
    for (int m = 0; m < 2; ++m)
#pragma unroll
      for (int nt = 0; nt < 4; ++nt)
#pragma unroll
        for (int reg = 0; reg < 4; ++reg) {
          const float val = fmaf(xxv[m][nt][reg], tmf4[nt] + acc2[m][nt][reg],
                                 xcv[m][nt][reg]);
          if (gout)
            gout[(size_t)(tok0 + m * 16 + half * 4 + reg) * CC + nt * 16 + col] = val;
          else
            xT[wid][m * 16 + half * 4 + reg][nt * 16 + col] = val;
        }
  };

  process_f(1, tm_k, xk_o);
  process_f(2, tm_v, xv_o);
  process_f(3, tm_r, xr_o);
  process_f(4, tm_g, xg_o);
  process_f(0, tm_w, nullptr);   // xw -> LDS xT

  short8 xwf[2][2];
#pragma unroll
  for (int m = 0; m < 2; ++m)
#pragma unroll
    for (int kk = 0; kk < 2; ++kk)
      xwf[m][kk] = ldb8_lds(&xT[wid][m * 16 + col][kk * 32 + half * 8]);
  f32x4 hcc[2][4];
#pragma unroll
  for (int m = 0; m < 2; ++m)
#pragma unroll
    for (int nt = 0; nt < 4; ++nt) hcc[m][nt] = (f32x4){0.f, 0.f, 0.f, 0.f};
  short8 bd[4][2];
#pragma unroll
  for (int nt = 0; nt < 4; ++nt)
#pragma unroll
    for (int kk = 0; kk < 2; ++kk)
      bd[nt][kk] = ldb8(d1T + (size_t)(nt * 16 + col) * 64 + kk * 32 + half * 8);
#pragma unroll
  for (int m = 0; m < 2; ++m)
#pragma unroll
    for (int nt = 0; nt < 4; ++nt)
#pragma unroll
      for (int kk = 0; kk < 2; ++kk)
        hcc[m][nt] = __builtin_amdgcn_mfma_f32_16x16x32_bf16(
            xwf[m][kk], bd[nt][kk], hcc[m][nt], 0, 0, 0);
#pragma unroll
  for (int m = 0; m < 2; ++m)
#pragma unroll
    for (int nt = 0; nt < 4; ++nt)
#pragma unroll
      for (int reg = 0; reg < 4; ++reg)
        xT[wid][m * 16 + half * 4 + reg][nt * 16 + col] = tanh_f(hcc[m][nt][reg]);
  short8 hf[2][2];
#pragma unroll
  for (int m = 0; m < 2; ++m)
#pragma unroll
    for (int kk = 0; kk < 2; ++kk)
      hf[m][kk] = ldb8_lds(&xT[wid][m * 16 + col][kk * 32 + half * 8]);
  f32x4 wfa[2][4];
#pragma unroll
  for (int m = 0; m < 2; ++m)
#pragma unroll
    for (int nt = 0; nt < 4; ++nt) wfa[m][nt] = (f32x4){0.f, 0.f, 0.f, 0.f};
#pragma unroll
  for (int nt = 0; nt < 4; ++nt)
#pragma unroll
    for (int kk = 0; kk < 2; ++kk)
      bd[nt][kk] = ldb8(d2T + (size_t)(nt * 16 + col) * 64 + kk * 32 + half * 8);
#pragma unroll
  for (int m = 0; m < 2; ++m)
#pragma unroll
    for (int nt = 0; nt < 4; ++nt)
#pragma unroll
      for (int kk = 0; kk < 2; ++kk)
        wfa[m][nt] = __builtin_amdgcn_mfma_f32_16x16x32_bf16(
            hf[m][kk], bd[nt][kk], wfa[m][nt], 0, 0, 0);
  float td4[4];
#pragma unroll
  for (int nt = 0; nt < 4; ++nt) td4[nt] = t_decay[nt * 16 + col];
#pragma unroll
  for (int m = 0; m < 2; ++m)
#pragma unroll
    for (int nt = 0; nt < 4; ++nt)
#pragma unroll
      for (int reg = 0; reg < 4; ++reg)
        rkdc[4 * ((size_t)(tok0 + m * 16 + half * 4 + reg) * CC + nt * 16 + col) + 2] =
            __expf(wfa[m][nt][reg] + td4[nt]);   // ew = exp(w), NOT d
}

// ---- proj4 via MFMA (bf16 3-product split) — unchanged -------------------
__device__ __forceinline__ void load_afrag(
    const float* __restrict__ X, int tok0, int col, int half,
    short8 ah[2][2], short8 al[2][2])
{
#pragma unroll
  for (int m = 0; m < 2; ++m)
#pragma unroll
    for (int kk = 0; kk < 2; ++kk)
      splitload(X + (size_t)(tok0 + m * 16 + col) * CC + kk * 32 + half * 8,
                ah[m][kk], al[m][kk]);
}
__device__ __forceinline__ void load_bfrag(
    const float* __restrict__ W, int col, int half,
    short8 bh[4][2], short8 bl[4][2])
{
#pragma unroll
  for (int n = 0; n < 4; ++n)
#pragma unroll
    for (int kk = 0; kk < 2; ++kk)
      splitload(W + (size_t)(n * 16 + col) * CC + kk * 32 + half * 8,
                bh[n][kk], bl[n][kk]);
}
__device__ __forceinline__ void gemm_acc(
    const short8 ah[2][2], const short8 al[2][2],
    const short8 bh[4][2], const short8 bl[4][2], f32x4 acc[2][4])
{
#pragma unroll
  for (int m = 0; m < 2; ++m)
#pragma unroll
    for (int n = 0; n < 4; ++n) {
      f32x4 a = acc[m][n];
#pragma unroll
      for (int kk = 0; kk < 2; ++kk)
        a = mfma3(ah[m][kk], al[m][kk], bh[n][kk], bl[n][kk], a);
      acc[m][n] = a;
    }
}

__global__ __launch_bounds__(256) void proj4_mfma_kernel(
    const float* __restrict__ xk_i, const float* __restrict__ xv_i,
    const float* __restrict__ xr_i, const float* __restrict__ xg_i,
    const float* __restrict__ u,
    const float* __restrict__ Wr, const float* __restrict__ Wk, const float* __restrict__ Wv,
    const float* __restrict__ Wg,
    float* __restrict__ rkdc, float* __restrict__ v_o, float* __restrict__ g_o)
{
  const int lane = threadIdx.x & 63;
  const int wid = threadIdx.x >> 6;
  const int col = lane & 15, half = lane >> 4;
  const int tok0 = blockIdx.x * 128 + wid * 32;

  short8 ah[2][2], al[2][2], bh[4][2], bl[4][2];
  f32x4 accr[2][4], acck[2][4];

  load_bfrag(Wr, col, half, bh, bl);
  load_afrag(xr_i, tok0, col, half, ah, al);
#pragma unroll
  for (int m = 0; m < 2; ++m)
#pragma unroll
    for (int n = 0; n < 4; ++n) accr[m][n] = (f32x4){0.f, 0.f, 0.f, 0.f};
  gemm_acc(ah, al, bh, bl, accr);

  load_bfrag(Wk, col, half, bh, bl);
  load_afrag(xk_i, tok0, col, half, ah, al);
#pragma unroll
  for (int m = 0; m < 2; ++m)
#pragma unroll
    for (int n = 0; n < 4; ++n) acck[m][n] = (f32x4){0.f, 0.f, 0.f, 0.f};
  gemm_acc(ah, al, bh, bl, acck);

  float uv[4];
#pragma unroll
  for (int n = 0; n < 4; ++n) uv[n] = u[n * 16 + col];
  float ctv[2][4];
#pragma unroll
  for (int m = 0; m < 2; ++m)
#pragma unroll
    for (int reg = 0; reg < 4; ++reg) {
      float p = 0.f;
#pragma unroll
      for (int n = 0; n < 4; ++n)
        p += accr[m][n][reg] * uv[n] * acck[m][n][reg];
      p += __shfl_xor(p, 1, 64);
      p += __shfl_xor(p, 2, 64);
      p += __shfl_xor(p, 4, 64);
      p += __shfl_xor(p, 8, 64);
      ctv[m][reg] = p;
    }

#pragma unroll
  for (int m = 0; m < 2; ++m)
#pragma unroll
    for (int n = 0; n < 4; ++n)
#pragma unroll
      for (int reg = 0; reg < 4; ++reg) {
        const int token = tok0 + m * 16 + half * 4 + reg;
        const size_t o = (size_t)token * CC + n * 16 + col;
        rkdc[4 * o + 0] = accr[m][n][reg];
        rkdc[4 * o + 1] = acck[m][n][reg];
        rkdc[4 * o + 3] = ctv[m][reg];
      }

  load_bfrag(Wv, col, half, bh, bl);
  load_afrag(xv_i, tok0, col, half, ah, al);
#pragma unroll
  for (int m = 0; m < 2; ++m)
#pragma unroll
    for (int n = 0; n < 4; ++n) accr[m][n] = (f32x4){0.f, 0.f, 0.f, 0.f};
  gemm_acc(ah, al, bh, bl, accr);
#pragma unroll
  for (int m = 0; m < 2; ++m)
#pragma unroll
    for (int n = 0; n < 4; ++n)
#pragma unroll
      for (int reg = 0; reg < 4; ++reg) {
        const int token = tok0 + m * 16 + half * 4 + reg;
        v_o[(size_t)token * CC + n * 16 + col] = accr[m][n][reg];
      }

  load_bfrag(Wg, col, half, bh, bl);
  load_afrag(xg_i, tok0, col, half, ah, al);
#pragma unroll
  for (int m = 0; m < 2; ++m)
#pragma unroll
    for (int n = 0; n < 4; ++n) accr[m][n] = (f32x4){0.f, 0.f, 0.f, 0.f};
  gemm_acc(ah, al, bh, bl, accr);
#pragma unroll
  for (int m = 0; m < 2; ++m)
#pragma unroll
    for (int n = 0; n < 4; ++n)
#pragma unroll
      for (int reg = 0; reg < 4; ++reg) {
        const int token = tok0 + m * 16 + half * 4 + reg;
        const float gg = accr[m][n][reg];
        g_o[(size_t)token * CC + n * 16 + col] = gg / (1.f + __expf(-gg));
      }
}

// ---- A (MFMA): S^T[j][i] = exp(-cumEnd[i]) * sum_s v[s][j] k~[s][i] ------
// Wave = (b,ch), 2 waves/block. lane=i for k~, lane=j for v.
__global__ __launch_bounds__(128) void chunkA_mfma_kernel(
    const float4* __restrict__ rkdc, const float* __restrict__ v_i,
    float* __restrict__ SlocT, float* __restrict__ Dp)
{
  __shared__ float ktS[2][64 * SW];   // k~T[i][s]
  __shared__ float vtS[2][64 * SW];   // vT[j][s]
  __shared__ float cumS[2][64];
  const int lane = threadIdx.x & 63;
  const int w = threadIdx.x >> 6;
  const int bch = __builtin_amdgcn_readfirstlane((blockIdx.x << 1) + w);
  float* ktL = ktS[w];
  float* vtL = vtS[w];
  float* cumL = cumS[w];
  const int col = lane & 15, half = lane >> 4;

  const float4* fq = rkdc + (size_t)bch * (CL * CC) + lane;
  const float* vq = v_i + (size_t)bch * (CL * CC) + lane;

  float cum = 0.f;
  for (int t = 0; t < CL; ++t) {
    const float4 f = fq[t * CC];
    const float vv = vq[t * CC];
    cum += f.z;                              // f.z = ew
    ktL[lane * SW + t] = f.y * __expf(cum);  // k~_t[i] = k * exp(cumAfter)
    vtL[lane * SW + t] = vv;
  }
  cumL[lane] = cum;
  Dp[(size_t)bch * CC + lane] = __expf(-cum);

  // A-frags: vT[j][s]; B-frags: k~T[i][s]; M=j(4), N=i(4), K=32(1 step)
  short8 vah[4], val[4], kbh[4], kbl[4];
#pragma unroll
  for (int m = 0; m < 4; ++m)
    splitload(vtL + (m * 16 + col) * SW + half * 8, vah[m], val[m]);
#pragma unroll
  for (int n = 0; n < 4; ++n)
    splitload(ktL + (n * 16 + col) * SW + half * 8, kbh[n], kbl[n]);

  f32x4 acc[4][4];
#pragma unroll
  for (int m = 0; m < 4; ++m)
#pragma unroll
    for (int n = 0; n < 4; ++n) {
      acc[m][n] = (f32x4){0.f, 0.f, 0.f, 0.f};
      acc[m][n] = mfma3(vah[m], val[m], kbh[n], kbl[n], acc[m][n]);
    }

  float acl[4];
#pragma unroll
  for (int n = 0; n < 4; ++n) acl[n] = __expf(-cumL[n * 16 + col]);

  float* so = SlocT + (size_t)bch * (CC * CC);
#pragma unroll
  for (int m = 0; m < 4; ++m)
#pragma unroll
    for (int n = 0; n < 4; ++n)
#pragma unroll
      for (int reg = 0; reg < 4; ++reg) {
        const int jj = m * 16 + half * 4 + reg;
        const int ii = n * 16 + col;
        so[jj * CC + ii] = acc[m][n][reg] * acl[n];
      }
}

// ---- B: in-place combine over chunks (transposed [j][i] layout) ----------
__global__ __launch_bounds__(1024) void combine_kernel(
    float* __restrict__ buf, const float* __restrict__ Dp)
{
  const int b = blockIdx.x, tid = threadIdx.x;
  __shared__ float sDp[NCH * CC];
  for (int idx = tid; idx < NCH * CC; idx += 1024)
    sDp[idx] = Dp[(size_t)b * NCH * CC + idx];
  __syncthreads();
  float run[4] = {0.f, 0.f, 0.f, 0.f};
  for (int ch = 0; ch < NCH; ++ch) {
    const size_t base = ((size_t)(b * NCH + ch)) * (CC * CC);
    const float* drow = sDp + ch * CC;
#pragma unroll
    for (int k2 = 0; k2 < 4; ++k2) {
      const int idx = tid + (k2 << 10);
      const float tmp = buf[base + idx];
      buf[base + idx] = run[k2];
      run[k2] = fmaf(run[k2], drow[idx & 63], tmp);
    }
  }
}

// ---- C (MFMA): y = mask(R~K~^T, diag<-ct)@V + R~@S0; GN; *g; @Wo^T -------
// Wave = (b,ch), 2 waves/block.
__global__ __launch_bounds__(128) void scanC_mfma_kernel(
    const float4* __restrict__ rkdc, const float* __restrict__ v_i,
    const float* __restrict__ S0T, const float* __restrict__ g_i,
    const float* __restrict__ ln_w, const float* __restrict__ ln_b,
    const float* __restrict__ Wo, float* __restrict__ out)
{
  __shared__ float rtS[2][32 * SA];   // r~[t][i]; later sz[t][c]
  __shared__ float ktS[2][32 * SA];   // k~[s][i]; later P[t][s]
  __shared__ float vtS[2][64 * SW];   // vT[j][s]
  __shared__ float ctS[2][CL];
  const int lane = threadIdx.x & 63;
  const int w = threadIdx.x >> 6;
  const int bch = __builtin_amdgcn_readfirstlane((blockIdx.x << 1) + w);
  float* rtL = rtS[w];
  float* ktL = ktS[w];
  float* vtL = vtS[w];
  float* ctL = ctS[w];
  const int col = lane & 15, half = lane >> 4;

  const float4* fq = rkdc + (size_t)bch * (CL * CC) + lane;
  const float* vq = v_i + (size_t)bch * (CL * CC) + lane;

  float cum = 0.f;
  for (int t = 0; t < CL; ++t) {
    const float4 f = fq[t * CC];
    const float vv = vq[t * CC];
    rtL[t * SA + lane] = f.x * __expf(-cum);  // r~ = r * exp(-cumBefore)
    cum += f.z;
    ktL[t * SA + lane] = f.y * __expf(cum);   // k~ = k * exp(cumAfter)
    vtL[lane * SW + t] = vv;
    if (lane == 0) ctL[t] = f.w;
  }

  // r~ A-frags: M=32(m2), K=64(kk2) — also reused for S0 GEMM
  short8 rah[2][2], ral[2][2];
#pragma unroll
  for (int m = 0; m < 2; ++m)
#pragma unroll
    for (int kk = 0; kk < 2; ++kk)
      splitload(rtL + (m * 16 + col) * SA + kk * 32 + half * 8, rah[m][kk], ral[m][kk]);
  // k~ B-frags: N=32(n2), K=64
  short8 kbh[2][2], kbl[2][2];
#pragma unroll
  for (int n = 0; n < 2; ++n)
#pragma unroll
    for (int kk = 0; kk < 2; ++kk)
      splitload(ktL + (n * 16 + col) * SA + kk * 32 + half * 8, kbh[n][kk], kbl[n][kk]);

  f32x4 pacc[2][2];
#pragma unroll
  for (int m = 0; m < 2; ++m)
#pragma unroll
    for (int n = 0; n < 2; ++n) {
      pacc[m][n] = (f32x4){0.f, 0.f, 0.f, 0.f};
#pragma unroll
      for (int kk = 0; kk < 2; ++kk)
        pacc[m][n] = mfma3(rah[m][kk], ral[m][kk], kbh[n][kk], kbl[n][kk], pacc[m][n]);
    }

  // mask + diag(ct), write P into ktL region as [t][s] stride SA
#pragma unroll
  for (int m = 0; m < 2; ++m)
#pragma unroll
    for (int n = 0; n < 2; ++n)
#pragma unroll
      for (int reg = 0; reg < 4; ++reg) {
        const int tt = m * 16 + half * 4 + reg;
        const int ss = n * 16 + col;
        const float pv = (ss < tt) ? pacc[m][n][reg] : (ss == tt ? ctL[tt] : 0.f);
        ktL[tt * SA + ss] = pv;
      }

  // P A-frags: M=32(m2), K=32(1 step)
  short8 pah[2], pal[2];
#pragma unroll
  for (int m = 0; m < 2; ++m)
    splitload(ktL + (m * 16 + col) * SA + half * 8, pah[m], pal[m]);
  // vT B-frags: N=64(n4), K=32
  short8 vbh[4], vbl[4];
#pragma unroll
  for (int n = 0; n < 4; ++n)
    splitload(vtL + (n * 16 + col) * SW + half * 8, vbh[n], vbl[n]);

  f32x4 yacc[2][4];
#pragma unroll
  for (int m = 0; m < 2; ++m)
#pragma unroll
    for (int n = 0; n < 4; ++n) {
      yacc[m][n] = (f32x4){0.f, 0.f, 0.f, 0.f};
      yacc[m][n] = mfma3(pah[m], pal[m], vbh[n], vbl[n], yacc[m][n]);
    }

  // + R~ @ S0 (B from global S0T[j][i], row stride 64)
  const float* s0b = S0T + (size_t)bch * (CC * CC);
#pragma unroll
  for (int kk = 0; kk < 2; ++kk) {
    short8 sbh[4], sbl[4];
#pragma unroll
    for (int n = 0; n < 4; ++n)
      splitload(s0b + (size_t)(n * 16 + col) * CC + kk * 32 + half * 8, sbh[n], sbl[n]);
#pragma unroll
    for (int m = 0; m < 2; ++m)
#pragma unroll
      for (int n = 0; n < 4; ++n)
        yacc[m][n] = mfma3(rah[m][kk], ral[m][kk], sbh[n], sbl[n], yacc[m][n]);
  }

  // GroupNorm across j (in-thread n-sum + 16-lane shfl) per (m,reg)
  float s1v[2][4], s2v[2][4];
#pragma unroll
  for (int m = 0; m < 2; ++m)
#pragma unroll
    for (int reg = 0; reg < 4; ++reg) {
      float a = 0.f, b2 = 0.f;
#pragma unroll
      for (int n = 0; n < 4; ++n) {
        const float y = yacc[m][n][reg];
        a += y; b2 += y * y;
      }
      a += __shfl_xor(a, 1, 64); b2 += __shfl_xor(b2, 1, 64);
      a += __shfl_xor(a, 2, 64); b2 += __shfl_xor(b2, 2, 64);
      a += __shfl_xor(a, 4, 64); b2 += __shfl_xor(b2, 4, 64);
      a += __shfl_xor(a, 8, 64); b2 += __shfl_xor(b2, 8, 64);
      s1v[m][reg] = a; s2v[m][reg] = b2;
    }

  // z*g -> szL (rtL region, [t][c] stride SA)
#pragma unroll
  for (int m = 0; m < 2; ++m)
#pragma unroll
    for (int n = 0; n < 4; ++n) {
      const int cj = n * 16 + col;
      const float lnw = ln_w[cj], lnb = ln_b[cj];
#pragma unroll
      for (int reg = 0; reg < 4; ++reg) {
        const int tt = m * 16 + half * 4 + reg;
        const float y = yacc[m][n][reg];
        const float mu = s1v[m][reg] * (1.f / CC);
        const float var = s2v[m][reg] * (1.f / CC) - mu * mu;
        const float z = (y - mu) * rsqrtf(var + GN_EPS) * lnw + lnb;
        const float gg = g_i[((size_t)bch * CL + tt) * CC + cj];
        rtL[tt * SA + cj] = z * gg;
      }
    }

  // out = sz @ Wo^T : A from rtL (M=32, K=64), B from Wo[j][c] (global)
  f32x4 oacc[2][4];
#pragma unroll
  for (int m = 0; m < 2; ++m)
#pragma unroll
    for (int n = 0; n < 4; ++n) oacc[m][n] = (f32x4){0.f, 0.f, 0.f, 0.f};
#pragma unroll
  for (int kk = 0; kk < 2; ++kk) {
    short8 zah[2], zal[2];
#pragma unroll
    for (int m = 0; m < 2; ++m)
      splitload(rtL + (m * 16 + col) * SA + kk * 32 + half * 8, zah[m], zal[m]);
    short8 wbh[4], wbl[4];
#pragma unroll
    for (int n = 0; n < 4; ++n)
      splitload(Wo + (size_t)(n * 16 + col) * CC + kk * 32 + half * 8, wbh[n], wbl[n]);
#pragma unroll
    for (int m = 0; m < 2; ++m)
#pragma unroll
      for (int n = 0; n < 4; ++n)
        oacc[m][n] = mfma3(zah[m], zal[m], wbh[n], wbl[n], oacc[m][n]);
  }

#pragma unroll
  for (int m = 0; m < 2; ++m)
#pragma unroll
    for (int n = 0; n < 4; ++n)
#pragma unroll
      for (int reg = 0; reg < 4; ++reg) {
        const int tt = m * 16 + half * 4 + reg;
        out[((size_t)bch * CL + tt) * CC + n * 16 + col] = oacc[m][n][reg];
      }
}

extern "C" void kernel_launch(void* const* d_in, const int* in_sizes, int n_in,
                              void* d_out, int out_size, void* d_ws, size_t ws_size,
                              hipStream_t stream) {
  const float* x       = (const float*)d_in[0];
  const float* tm_x    = (const float*)d_in[1];
  const float* tm_w    = (const float*)d_in[2];
  const float* tm_k    = (const float*)d_in[3];
  const float* tm_v    = (const float*)d_in[4];
  const float* tm_r    = (const float*)d_in[5];
  const float* tm_g    = (const float*)d_in[6];
  const float* maa_w1  = (const float*)d_in[7];
  const float* maa_w2  = (const float*)d_in[8];
  const float* t_decay = (const float*)d_in[9];
  const float* dec_w1  = (const float*)d_in[10];
  const float* dec_w2  = (const float*)d_in[11];
  const float* u       = (const float*)d_in[12];
  const float* Wr      = (const float*)d_in[13];
  const float* Wk      = (const float*)d_in[14];
  const float* Wv      = (const float*)d_in[15];
  const float* Wg      = (const float*)d_in[16];
  const float* Wo      = (const float*)d_in[17];
  const float* ln_w    = (const float*)d_in[18];
  const float* ln_b    = (const float*)d_in[19];

  const size_t M = (size_t)BT * CC;  // 4.19M floats
  float* ws   = (float*)d_ws;
  float* xk_o = ws;                  // [0,M)   dead after proj4
  float* xv_o = ws + M;              // [M,2M)  dead after proj4
  float* xr_o = ws + 2 * M;          // [2M,3M) dead after proj4
  float* xg_o = ws + 3 * M;          // [3M,4M) dead after proj4
  float* g_o  = ws + 4 * M;          // alive until scanC
  float* v_o  = ws + 5 * M;          // alive until scanC
  float* rkdc = ws + 6 * M;          // [6M,10M) float4 stream
  float* scb  = ws;                  // SlocT==S0T (in-place), 2M floats
  float* Dp   = ws + 2 * M;          // aliases dead xr_o
  float* w1T  = ws + 10 * M;         // 10240
  float* w2T  = w1T + 160 * 64;      // 10240
  float* d1T  = w2T + 5 * 64 * 32;   // 4096
  float* d2T  = d1T + 4096;          // 4096
  float* out  = (float*)d_out;

  preT_kernel<<<64, 256, 0, stream>>>(
      maa_w1, maa_w2, dec_w1, dec_w2, w1T, w2T, d1T, d2T);

  mix_mfma_kernel<<<BT / 128, 256, 0, stream>>>(
      x, tm_x, tm_w, tm_k, tm_v, tm_r, tm_g,
      w1T, w2T, d1T, d2T, t_decay,
      xk_o, xv_o, xr_o, xg_o, rkdc);

  proj4_mfma_kernel<<<BT / 128, 256, 0, stream>>>(
      xk_o, xv_o, xr_o, xg_o, u, Wr, Wk, Wv, Wg, rkdc, v_o, g_o);

  chunkA_mfma_kernel<<<(BB * NCH) / 2, 128, 0, stream>>>(
      (const float4*)rkdc, v_o, scb, Dp);

  combine_kernel<<<BB, 1024, 0, stream>>>(scb, Dp);

  scanC_mfma_kernel<<<(BB * NCH) / 2, 128, 0, stream>>>(
      (const float4*)rkdc, v_o, scb, g_o, ln_w, ln_b, Wo, out);
}

// Round 17
// 171.189 us; speedup vs baseline: 2.0151x; 1.1404x over previous
//
#include <hip/hip_runtime.h>

#define BB 32
#define TT 2048
#define CC 64
#define BT (BB * TT)
#define NCH 64
#define CL 32  // chunk length; NCH*CL == TT
#define GN_EPS (1e-5f * 64.f)
#define SW 36  // vT / k~T LDS stride
#define SA 68  // [t][i]-style LDS stride

typedef short short8 __attribute__((ext_vector_type(8)));
typedef float f32x4 __attribute__((ext_vector_type(4)));

// ---- helpers -------------------------------------------------------------
__device__ __forceinline__ float tanh_f(float x) {
  x = fminf(fmaxf(x, -10.f), 10.f);
  const float e = __expf(2.f * x);
  return (e - 1.f) / (e + 1.f);
}
__device__ __forceinline__ unsigned short f2bf(float x) {
  unsigned int u = __float_as_uint(x);
  u += 0x7FFFu + ((u >> 16) & 1u);   // RNE
  return (unsigned short)(u >> 16);
}
__device__ __forceinline__ float bf2f(unsigned short h) {
  return __uint_as_float(((unsigned int)h) << 16);
}
__device__ __forceinline__ short8 cvt8(const float4 a, const float4 b) {
  short8 h;
  h[0] = (short)f2bf(a.x); h[1] = (short)f2bf(a.y);
  h[2] = (short)f2bf(a.z); h[3] = (short)f2bf(a.w);
  h[4] = (short)f2bf(b.x); h[5] = (short)f2bf(b.y);
  h[6] = (short)f2bf(b.z); h[7] = (short)f2bf(b.w);
  return h;
}
__device__ __forceinline__ short8 ldb8(const float* p) {
  const float4 v0 = *reinterpret_cast<const float4*>(p);
  const float4 v1 = *reinterpret_cast<const float4*>(p + 4);
  return cvt8(v0, v1);
}
__device__ __forceinline__ void splitload(const float* p, short8& h8, short8& l8) {
  const float4 v0 = *reinterpret_cast<const float4*>(p);
  const float4 v1 = *reinterpret_cast<const float4*>(p + 4);
  const float vv[8] = {v0.x, v0.y, v0.z, v0.w, v1.x, v1.y, v1.z, v1.w};
#pragma unroll
  for (int e = 0; e < 8; ++e) {
    const unsigned short hb = f2bf(vv[e]);
    h8[e] = (short)hb;
    l8[e] = (short)f2bf(vv[e] - bf2f(hb));
  }
}
__device__ __forceinline__ f32x4 mfma3(short8 ah, short8 al, short8 bh, short8 bl, f32x4 a) {
  a = __builtin_amdgcn_mfma_f32_16x16x32_bf16(ah, bh, a, 0, 0, 0);
  a = __builtin_amdgcn_mfma_f32_16x16x32_bf16(ah, bl, a, 0, 0, 0);
  a = __builtin_amdgcn_mfma_f32_16x16x32_bf16(al, bh, a, 0, 0, 0);
  return a;
}

// ---- preT ----------------------------------------------------------------
__global__ __launch_bounds__(256) void preT_kernel(
    const float* __restrict__ maa_w1, const float* __restrict__ maa_w2,
    const float* __restrict__ dec_w1, const float* __restrict__ dec_w2,
    float* __restrict__ w1T, float* __restrict__ w2T,
    float* __restrict__ d1T, float* __restrict__ d2T)
{
  const int t0 = blockIdx.x * 256 + threadIdx.x;
  const int stride = gridDim.x * 256;
  for (int i = t0; i < 160 * 64; i += stride) {
    const int n = i >> 6, c = i & 63;
    w1T[i] = maa_w1[c * 160 + n];
  }
  for (int i = t0; i < 5 * 64 * 32; i += stride) {
    const int f = i >> 11, rem = i & 2047, n = rem >> 5, q = rem & 31;
    w2T[i] = maa_w2[(f * 32 + q) * 64 + n];
  }
  for (int i = t0; i < 4096; i += stride) {
    const int n = i >> 6, c = i & 63;
    d1T[i] = dec_w1[c * 64 + n];
    d2T[i] = dec_w2[c * 64 + n];
  }
}

// ---- prep_fused: token-shift + mixing + decay + 4 projections + ct -------
// Wave = 32 tokens; streams bounce through wave-private LDS, never HBM.
#define LDS_A 36
#define LDS_X 68
__global__ __launch_bounds__(256) void prep_fused_kernel(
    const float* __restrict__ x,
    const float* __restrict__ tm_x, const float* __restrict__ tm_w, const float* __restrict__ tm_k,
    const float* __restrict__ tm_v, const float* __restrict__ tm_r, const float* __restrict__ tm_g,
    const float* __restrict__ w1T, const float* __restrict__ w2T,
    const float* __restrict__ d1T, const float* __restrict__ d2T,
    const float* __restrict__ t_decay, const float* __restrict__ u,
    const float* __restrict__ Wr, const float* __restrict__ Wk,
    const float* __restrict__ Wv, const float* __restrict__ Wg,
    float* __restrict__ rkdc, float* __restrict__ v_o, float* __restrict__ g_o)
{
  __shared__ float aT[4][32][LDS_A];
  __shared__ float xT[4][32][LDS_X];
  const int lane = threadIdx.x & 63;
  const int wid = threadIdx.x >> 6;
  const int col = lane & 15, half = lane >> 4;
  const int tok0 = blockIdx.x * 128 + wid * 32;

  // A-layout xxx fragments
  short8 xa[2][2];
#pragma unroll
  for (int m = 0; m < 2; ++m)
#pragma unroll
    for (int kk = 0; kk < 2; ++kk) {
      const int tok = tok0 + m * 16 + col;
      const int kb = kk * 32 + half * 8;
      const float* pc = x + (size_t)tok * CC + kb;
      const float4 c0 = *reinterpret_cast<const float4*>(pc);
      const float4 c1 = *reinterpret_cast<const float4*>(pc + 4);
      float4 p0 = {0.f, 0.f, 0.f, 0.f}, p1 = {0.f, 0.f, 0.f, 0.f};
      if ((tok & (TT - 1)) != 0) {
        p0 = *reinterpret_cast<const float4*>(pc - CC);
        p1 = *reinterpret_cast<const float4*>(pc - CC + 4);
      }
      const float4 t0 = *reinterpret_cast<const float4*>(tm_x + kb);
      const float4 t1 = *reinterpret_cast<const float4*>(tm_x + kb + 4);
      const float cv[8] = {c0.x, c0.y, c0.z, c0.w, c1.x, c1.y, c1.z, c1.w};
      const float pv[8] = {p0.x, p0.y, p0.z, p0.w, p1.x, p1.y, p1.z, p1.w};
      const float tv[8] = {t0.x, t0.y, t0.z, t0.w, t1.x, t1.y, t1.z, t1.w};
      short8 h;
#pragma unroll
      for (int e = 0; e < 8; ++e)
        h[e] = (short)f2bf(fmaf(pv[e] - cv[e], tv[e], cv[e]));
      xa[m][kk] = h;
    }

  // C-layout xc/xx
  float xcv[2][4][4], xxv[2][4][4];
#pragma unroll
  for (int m = 0; m < 2; ++m)
#pragma unroll
    for (int reg = 0; reg < 4; ++reg) {
      const int tok = tok0 + m * 16 + half * 4 + reg;
      const bool has = (tok & (TT - 1)) != 0;
#pragma unroll
      for (int nt = 0; nt < 4; ++nt) {
        const size_t o = (size_t)tok * CC + nt * 16 + col;
        const float cur = x[o];
        const float prv = has ? x[o - CC] : 0.f;
        xcv[m][nt][reg] = cur;
        xxv[m][nt][reg] = prv - cur;
      }
    }

  // mixing pipeline: produce xf in C-layout, store to wave LDS xT[t][c]
  auto mix_f = [&](int f, const float* __restrict__ tmf) {
    f32x4 acc1[2][2];
#pragma unroll
    for (int m = 0; m < 2; ++m)
#pragma unroll
      for (int ntf = 0; ntf < 2; ++ntf) acc1[m][ntf] = (f32x4){0.f, 0.f, 0.f, 0.f};
    short8 b1[2][2];
#pragma unroll
    for (int ntf = 0; ntf < 2; ++ntf)
#pragma unroll
      for (int kk = 0; kk < 2; ++kk)
        b1[ntf][kk] = ldb8(w1T + (size_t)(f * 32 + ntf * 16 + col) * 64 + kk * 32 + half * 8);
#pragma unroll
    for (int m = 0; m < 2; ++m)
#pragma unroll
      for (int ntf = 0; ntf < 2; ++ntf)
#pragma unroll
        for (int kk = 0; kk < 2; ++kk)
          acc1[m][ntf] = __builtin_amdgcn_mfma_f32_16x16x32_bf16(
              xa[m][kk], b1[ntf][kk], acc1[m][ntf], 0, 0, 0);
#pragma unroll
    for (int m = 0; m < 2; ++m)
#pragma unroll
      for (int ntf = 0; ntf < 2; ++ntf)
#pragma unroll
        for (int reg = 0; reg < 4; ++reg)
          aT[wid][m * 16 + half * 4 + reg][ntf * 16 + col] = tanh_f(acc1[m][ntf][reg]);
    short8 a2[2];
#pragma unroll
    for (int m = 0; m < 2; ++m)
      a2[m] = ldb8(&aT[wid][m * 16 + col][half * 8]);
    f32x4 acc2[2][4];
#pragma unroll
    for (int m = 0; m < 2; ++m)
#pragma unroll
      for (int nt = 0; nt < 4; ++nt) acc2[m][nt] = (f32x4){0.f, 0.f, 0.f, 0.f};
    short8 b2[4];
#pragma unroll
    for (int nt = 0; nt < 4; ++nt)
      b2[nt] = ldb8(w2T + (size_t)f * 2048 + (nt * 16 + col) * 32 + half * 8);
#pragma unroll
    for (int m = 0; m < 2; ++m)
#pragma unroll
      for (int nt = 0; nt < 4; ++nt)
        acc2[m][nt] = __builtin_amdgcn_mfma_f32_16x16x32_bf16(
            a2[m], b2[nt], acc2[m][nt], 0, 0, 0);
    float tmf4[4];
#pragma unroll
    for (int nt = 0; nt < 4; ++nt) tmf4[nt] = tmf[nt * 16 + col];
#pragma unroll
    for (int m = 0; m < 2; ++m)
#pragma unroll
      for (int nt = 0; nt < 4; ++nt)
#pragma unroll
        for (int reg = 0; reg < 4; ++reg)
          xT[wid][m * 16 + half * 4 + reg][nt * 16 + col] =
              fmaf(xxv[m][nt][reg], tmf4[nt] + acc2[m][nt][reg], xcv[m][nt][reg]);
  };
  // A-layout 3-product fragments of the stream currently in xT
  auto xT_afrag = [&](short8 ah[2][2], short8 al[2][2]) {
#pragma unroll
    for (int m = 0; m < 2; ++m)
#pragma unroll
      for (int kk = 0; kk < 2; ++kk)
        splitload(&xT[wid][m * 16 + col][kk * 32 + half * 8], ah[m][kk], al[m][kk]);
  };
  // proj GEMM vs weight W (row-major [out][in]), 3-product
  auto proj_gemm = [&](const float* __restrict__ W, const short8 ah[2][2],
                       const short8 al[2][2], f32x4 acc[2][4]) {
#pragma unroll
    for (int m = 0; m < 2; ++m)
#pragma unroll
      for (int n = 0; n < 4; ++n) acc[m][n] = (f32x4){0.f, 0.f, 0.f, 0.f};
#pragma unroll
    for (int n = 0; n < 4; ++n)
#pragma unroll
      for (int kk = 0; kk < 2; ++kk) {
        short8 bh, bl;
        splitload(W + (size_t)(n * 16 + col) * CC + kk * 32 + half * 8, bh, bl);
#pragma unroll
        for (int m = 0; m < 2; ++m)
          acc[m][n] = mfma3(ah[m][kk], al[m][kk], bh, bl, acc[m][n]);
      }
  };

  short8 ah[2][2], al[2][2];

  // ---- phase W: xw -> decay MLP -> ew (held in regs) ----
  mix_f(0, tm_w);
  short8 xwh[2][2];
#pragma unroll
  for (int m = 0; m < 2; ++m)
#pragma unroll
    for (int kk = 0; kk < 2; ++kk)
      xwh[m][kk] = ldb8(&xT[wid][m * 16 + col][kk * 32 + half * 8]);
  f32x4 hcc[2][4];
#pragma unroll
  for (int m = 0; m < 2; ++m)
#pragma unroll
    for (int nt = 0; nt < 4; ++nt) hcc[m][nt] = (f32x4){0.f, 0.f, 0.f, 0.f};
#pragma unroll
  for (int nt = 0; nt < 4; ++nt)
#pragma unroll
    for (int kk = 0; kk < 2; ++kk) {
      const short8 bd = ldb8(d1T + (size_t)(nt * 16 + col) * 64 + kk * 32 + half * 8);
#pragma unroll
      for (int m = 0; m < 2; ++m)
        hcc[m][nt] = __builtin_amdgcn_mfma_f32_16x16x32_bf16(
            xwh[m][kk], bd, hcc[m][nt], 0, 0, 0);
    }
#pragma unroll
  for (int m = 0; m < 2; ++m)
#pragma unroll
    for (int nt = 0; nt < 4; ++nt)
#pragma unroll
      for (int reg = 0; reg < 4; ++reg)
        xT[wid][m * 16 + half * 4 + reg][nt * 16 + col] = tanh_f(hcc[m][nt][reg]);
#pragma unroll
  for (int m = 0; m < 2; ++m)
#pragma unroll
    for (int kk = 0; kk < 2; ++kk)
      xwh[m][kk] = ldb8(&xT[wid][m * 16 + col][kk * 32 + half * 8]);
  f32x4 wfa[2][4];
#pragma unroll
  for (int m = 0; m < 2; ++m)
#pragma unroll
    for (int nt = 0; nt < 4; ++nt) wfa[m][nt] = (f32x4){0.f, 0.f, 0.f, 0.f};
#pragma unroll
  for (int nt = 0; nt < 4; ++nt)
#pragma unroll
    for (int kk = 0; kk < 2; ++kk) {
      const short8 bd = ldb8(d2T + (size_t)(nt * 16 + col) * 64 + kk * 32 + half * 8);
#pragma unroll
      for (int m = 0; m < 2; ++m)
        wfa[m][nt] = __builtin_amdgcn_mfma_f32_16x16x32_bf16(
            xwh[m][kk], bd, wfa[m][nt], 0, 0, 0);
    }
  float ewv[2][4][4];
  {
    float td4[4];
#pragma unroll
    for (int nt = 0; nt < 4; ++nt) td4[nt] = t_decay[nt * 16 + col];
#pragma unroll
    for (int m = 0; m < 2; ++m)
#pragma unroll
      for (int nt = 0; nt < 4; ++nt)
#pragma unroll
        for (int reg = 0; reg < 4; ++reg)
          ewv[m][nt][reg] = __expf(wfa[m][nt][reg] + td4[nt]);
  }

  // ---- phase R ----
  mix_f(3, tm_r);
  xT_afrag(ah, al);
  f32x4 accr[2][4];
  proj_gemm(Wr, ah, al, accr);

  // ---- phase K + ct + full rkdc write ----
  mix_f(1, tm_k);
  xT_afrag(ah, al);
  f32x4 acck[2][4];
  proj_gemm(Wk, ah, al, acck);

  float uv[4];
#pragma unroll
  for (int n = 0; n < 4; ++n) uv[n] = u[n * 16 + col];
#pragma unroll
  for (int m = 0; m < 2; ++m) {
    float ctv[4];
#pragma unroll
    for (int reg = 0; reg < 4; ++reg) {
      float p = 0.f;
#pragma unroll
      for (int n = 0; n < 4; ++n)
        p += accr[m][n][reg] * uv[n] * acck[m][n][reg];
      p += __shfl_xor(p, 1, 64);
      p += __shfl_xor(p, 2, 64);
      p += __shfl_xor(p, 4, 64);
      p += __shfl_xor(p, 8, 64);
      ctv[reg] = p;
    }
#pragma unroll
    for (int n = 0; n < 4; ++n)
#pragma unroll
      for (int reg = 0; reg < 4; ++reg) {
        const int token = tok0 + m * 16 + half * 4 + reg;
        const size_t o = (size_t)token * CC + n * 16 + col;
        *reinterpret_cast<float4*>(rkdc + 4 * o) =
            make_float4(accr[m][n][reg], acck[m][n][reg], ewv[m][n][reg], ctv[reg]);
      }
  }

  // ---- phase V ----
  mix_f(2, tm_v);
  xT_afrag(ah, al);
  proj_gemm(Wv, ah, al, accr);
#pragma unroll
  for (int m = 0; m < 2; ++m)
#pragma unroll
    for (int n = 0; n < 4; ++n)
#pragma unroll
      for (int reg = 0; reg < 4; ++reg) {
        const int token = tok0 + m * 16 + half * 4 + reg;
        v_o[(size_t)token * CC + n * 16 + col] = accr[m][n][reg];
      }

  // ---- phase G ----
  mix_f(4, tm_g);
  xT_afrag(ah, al);
  proj_gemm(Wg, ah, al, accr);
#pragma unroll
  for (int m = 0; m < 2; ++m)
#pragma unroll
    for (int n = 0; n < 4; ++n)
#pragma unroll
      for (int reg = 0; reg < 4; ++reg) {
        const int token = tok0 + m * 16 + half * 4 + reg;
        const float gg = accr[m][n][reg];
        g_o[(size_t)token * CC + n * 16 + col] = gg / (1.f + __expf(-gg));
      }
}

// ---- A (MFMA): S^T[j][i] = exp(-cumEnd[i]) * sum_s v[s][j] k~[s][i] ------
__global__ __launch_bounds__(128) void chunkA_mfma_kernel(
    const float4* __restrict__ rkdc, const float* __restrict__ v_i,
    float* __restrict__ SlocT, float* __restrict__ Dp)
{
  __shared__ float ktS[2][64 * SW];
  __shared__ float vtS[2][64 * SW];
  __shared__ float cumS[2][64];
  const int lane = threadIdx.x & 63;
  const int w = threadIdx.x >> 6;
  const int bch = __builtin_amdgcn_readfirstlane((blockIdx.x << 1) + w);
  float* ktL = ktS[w];
  float* vtL = vtS[w];
  float* cumL = cumS[w];
  const int col = lane & 15, half = lane >> 4;

  const float4* fq = rkdc + (size_t)bch * (CL * CC) + lane;
  const float* vq = v_i + (size_t)bch * (CL * CC) + lane;

  float cum = 0.f;
  for (int t = 0; t < CL; ++t) {
    const float4 f = fq[t * CC];
    const float vv = vq[t * CC];
    cum += f.z;
    ktL[lane * SW + t] = f.y * __expf(cum);
    vtL[lane * SW + t] = vv;
  }
  cumL[lane] = cum;
  Dp[(size_t)bch * CC + lane] = __expf(-cum);

  short8 vah[4], val[4], kbh[4], kbl[4];
#pragma unroll
  for (int m = 0; m < 4; ++m)
    splitload(vtL + (m * 16 + col) * SW + half * 8, vah[m], val[m]);
#pragma unroll
  for (int n = 0; n < 4; ++n)
    splitload(ktL + (n * 16 + col) * SW + half * 8, kbh[n], kbl[n]);

  f32x4 acc[4][4];
#pragma unroll
  for (int m = 0; m < 4; ++m)
#pragma unroll
    for (int n = 0; n < 4; ++n) {
      acc[m][n] = (f32x4){0.f, 0.f, 0.f, 0.f};
      acc[m][n] = mfma3(vah[m], val[m], kbh[n], kbl[n], acc[m][n]);
    }

  float acl[4];
#pragma unroll
  for (int n = 0; n < 4; ++n) acl[n] = __expf(-cumL[n * 16 + col]);

  float* so = SlocT + (size_t)bch * (CC * CC);
#pragma unroll
  for (int m = 0; m < 4; ++m)
#pragma unroll
    for (int n = 0; n < 4; ++n)
#pragma unroll
      for (int reg = 0; reg < 4; ++reg) {
        const int jj = m * 16 + half * 4 + reg;
        const int ii = n * 16 + col;
        so[jj * CC + ii] = acc[m][n][reg] * acl[n];
      }
}

// ---- B: in-place combine over chunks (transposed [j][i] layout) ----------
__global__ __launch_bounds__(1024) void combine_kernel(
    float* __restrict__ buf, const float* __restrict__ Dp)
{
  const int b = blockIdx.x, tid = threadIdx.x;
  __shared__ float sDp[NCH * CC];
  for (int idx = tid; idx < NCH * CC; idx += 1024)
    sDp[idx] = Dp[(size_t)b * NCH * CC + idx];
  __syncthreads();
  float run[4] = {0.f, 0.f, 0.f, 0.f};
  for (int ch = 0; ch < NCH; ++ch) {
    const size_t base = ((size_t)(b * NCH + ch)) * (CC * CC);
    const float* drow = sDp + ch * CC;
#pragma unroll
    for (int k2 = 0; k2 < 4; ++k2) {
      const int idx = tid + (k2 << 10);
      const float tmp = buf[base + idx];
      buf[base + idx] = run[k2];
      run[k2] = fmaf(run[k2], drow[idx & 63], tmp);
    }
  }
}

// ---- C (MFMA): y = mask(R~K~^T, diag<-ct)@V + R~@S0; GN; *g; @Wo^T -------
__global__ __launch_bounds__(128) void scanC_mfma_kernel(
    const float4* __restrict__ rkdc, const float* __restrict__ v_i,
    const float* __restrict__ S0T, const float* __restrict__ g_i,
    const float* __restrict__ ln_w, const float* __restrict__ ln_b,
    const float* __restrict__ Wo, float* __restrict__ out)
{
  __shared__ float rtS[2][32 * SA];
  __shared__ float ktS[2][32 * SA];
  __shared__ float vtS[2][64 * SW];
  __shared__ float ctS[2][CL];
  const int lane = threadIdx.x & 63;
  const int w = threadIdx.x >> 6;
  const int bch = __builtin_amdgcn_readfirstlane((blockIdx.x << 1) + w);
  float* rtL = rtS[w];
  float* ktL = ktS[w];
  float* vtL = vtS[w];
  float* ctL = ctS[w];
  const int col = lane & 15, half = lane >> 4;

  const float4* fq = rkdc + (size_t)bch * (CL * CC) + lane;
  const float* vq = v_i + (size_t)bch * (CL * CC) + lane;

  float cum = 0.f;
  for (int t = 0; t < CL; ++t) {
    const float4 f = fq[t * CC];
    const float vv = vq[t * CC];
    rtL[t * SA + lane] = f.x * __expf(-cum);
    cum += f.z;
    ktL[t * SA + lane] = f.y * __expf(cum);
    vtL[lane * SW + t] = vv;
    if (lane == 0) ctL[t] = f.w;
  }

  short8 rah[2][2], ral[2][2];
#pragma unroll
  for (int m = 0; m < 2; ++m)
#pragma unroll
    for (int kk = 0; kk < 2; ++kk)
      splitload(rtL + (m * 16 + col) * SA + kk * 32 + half * 8, rah[m][kk], ral[m][kk]);
  short8 kbh[2][2], kbl[2][2];
#pragma unroll
  for (int n = 0; n < 2; ++n)
#pragma unroll
    for (int kk = 0; kk < 2; ++kk)
      splitload(ktL + (n * 16 + col) * SA + kk * 32 + half * 8, kbh[n][kk], kbl[n][kk]);

  f32x4 pacc[2][2];
#pragma unroll
  for (int m = 0; m < 2; ++m)
#pragma unroll
    for (int n = 0; n < 2; ++n) {
      pacc[m][n] = (f32x4){0.f, 0.f, 0.f, 0.f};
#pragma unroll
      for (int kk = 0; kk < 2; ++kk)
        pacc[m][n] = mfma3(rah[m][kk], ral[m][kk], kbh[n][kk], kbl[n][kk], pacc[m][n]);
    }

#pragma unroll
  for (int m = 0; m < 2; ++m)
#pragma unroll
    for (int n = 0; n < 2; ++n)
#pragma unroll
      for (int reg = 0; reg < 4; ++reg) {
        const int tt = m * 16 + half * 4 + reg;
        const int ss = n * 16 + col;
        const float pv = (ss < tt) ? pacc[m][n][reg] : (ss == tt ? ctL[tt] : 0.f);
        ktL[tt * SA + ss] = pv;
      }

  short8 pah[2], pal[2];
#pragma unroll
  for (int m = 0; m < 2; ++m)
    splitload(ktL + (m * 16 + col) * SA + half * 8, pah[m], pal[m]);
  short8 vbh[4], vbl[4];
#pragma unroll
  for (int n = 0; n < 4; ++n)
    splitload(vtL + (n * 16 + col) * SW + half * 8, vbh[n], vbl[n]);

  f32x4 yacc[2][4];
#pragma unroll
  for (int m = 0; m < 2; ++m)
#pragma unroll
    for (int n = 0; n < 4; ++n) {
      yacc[m][n] = (f32x4){0.f, 0.f, 0.f, 0.f};
      yacc[m][n] = mfma3(pah[m], pal[m], vbh[n], vbl[n], yacc[m][n]);
    }

  const float* s0b = S0T + (size_t)bch * (CC * CC);
#pragma unroll
  for (int kk = 0; kk < 2; ++kk) {
    short8 sbh[4], sbl[4];
#pragma unroll
    for (int n = 0; n < 4; ++n)
      splitload(s0b + (size_t)(n * 16 + col) * CC + kk * 32 + half * 8, sbh[n], sbl[n]);
#pragma unroll
    for (int m = 0; m < 2; ++m)
#pragma unroll
      for (int n = 0; n < 4; ++n)
        yacc[m][n] = mfma3(rah[m][kk], ral[m][kk], sbh[n], sbl[n], yacc[m][n]);
  }

  float s1v[2][4], s2v[2][4];
#pragma unroll
  for (int m = 0; m < 2; ++m)
#pragma unroll
    for (int reg = 0; reg < 4; ++reg) {
      float a = 0.f, b2 = 0.f;
#pragma unroll
      for (int n = 0; n < 4; ++n) {
        const float y = yacc[m][n][reg];
        a += y; b2 += y * y;
      }
      a += __shfl_xor(a, 1, 64); b2 += __shfl_xor(b2, 1, 64);
      a += __shfl_xor(a, 2, 64); b2 += __shfl_xor(b2, 2, 64);
      a += __shfl_xor(a, 4, 64); b2 += __shfl_xor(b2, 4, 64);
      a += __shfl_xor(a, 8, 64); b2 += __shfl_xor(b2, 8, 64);
      s1v[m][reg] = a; s2v[m][reg] = b2;
    }

#pragma unroll
  for (int m = 0; m < 2; ++m)
#pragma unroll
    for (int n = 0; n < 4; ++n) {
      const int cj = n * 16 + col;
      const float lnw = ln_w[cj], lnb = ln_b[cj];
#pragma unroll
      for (int reg = 0; reg < 4; ++reg) {
        const int tt = m * 16 + half * 4 + reg;
        const float y = yacc[m][n][reg];
        const float mu = s1v[m][reg] * (1.f / CC);
        const float var = s2v[m][reg] * (1.f / CC) - mu * mu;
        const float z = (y - mu) * rsqrtf(var + GN_EPS) * lnw + lnb;
        const float gg = g_i[((size_t)bch * CL + tt) * CC + cj];
        rtL[tt * SA + cj] = z * gg;
      }
    }

  f32x4 oacc[2][4];
#pragma unroll
  for (int m = 0; m < 2; ++m)
#pragma unroll
    for (int n = 0; n < 4; ++n) oacc[m][n] = (f32x4){0.f, 0.f, 0.f, 0.f};
#pragma unroll
  for (int kk = 0; kk < 2; ++kk) {
    short8 zah[2], zal[2];
#pragma unroll
    for (int m = 0; m < 2; ++m)
      splitload(rtL + (m * 16 + col) * SA + kk * 32 + half * 8, zah[m], zal[m]);
    short8 wbh[4], wbl[4];
#pragma unroll
    for (int n = 0; n < 4; ++n)
      splitload(Wo + (size_t)(n * 16 + col) * CC + kk * 32 + half * 8, wbh[n], wbl[n]);
#pragma unroll
    for (int m = 0; m < 2; ++m)
#pragma unroll
      for (int n = 0; n < 4; ++n)
        oacc[m][n] = mfma3(zah[m], zal[m], wbh[n], wbl[n], oacc[m][n]);
  }

#pragma unroll
  for (int m = 0; m < 2; ++m)
#pragma unroll
    for (int n = 0; n < 4; ++n)
#pragma unroll
      for (int reg = 0; reg < 4; ++reg) {
        const int tt = m * 16 + half * 4 + reg;
        out[((size_t)bch * CL + tt) * CC + n * 16 + col] = oacc[m][n][reg];
      }
}

extern "C" void kernel_launch(void* const* d_in, const int* in_sizes, int n_in,
                              void* d_out, int out_size, void* d_ws, size_t ws_size,
                              hipStream_t stream) {
  const float* x       = (const float*)d_in[0];
  const float* tm_x    = (const float*)d_in[1];
  const float* tm_w    = (const float*)d_in[2];
  const float* tm_k    = (const float*)d_in[3];
  const float* tm_v    = (const float*)d_in[4];
  const float* tm_r    = (const float*)d_in[5];
  const float* tm_g    = (const float*)d_in[6];
  const float* maa_w1  = (const float*)d_in[7];
  const float* maa_w2  = (const float*)d_in[8];
  const float* t_decay = (const float*)d_in[9];
  const float* dec_w1  = (const float*)d_in[10];
  const float* dec_w2  = (const float*)d_in[11];
  const float* u       = (const float*)d_in[12];
  const float* Wr      = (const float*)d_in[13];
  const float* Wk      = (const float*)d_in[14];
  const float* Wv      = (const float*)d_in[15];
  const float* Wg      = (const float*)d_in[16];
  const float* Wo      = (const float*)d_in[17];
  const float* ln_w    = (const float*)d_in[18];
  const float* ln_b    = (const float*)d_in[19];

  const size_t M = (size_t)BT * CC;  // 4.19M floats
  float* ws   = (float*)d_ws;
  float* g_o  = ws + 4 * M;          // alive until scanC
  float* v_o  = ws + 5 * M;          // alive until scanC
  float* rkdc = ws + 6 * M;          // [6M,10M) float4 stream
  float* scb  = ws;                  // SlocT==S0T (in-place), 2M floats
  float* Dp   = ws + 2 * M;
  float* w1T  = ws + 10 * M;
  float* w2T  = w1T + 160 * 64;
  float* d1T  = w2T + 5 * 64 * 32;
  float* d2T  = d1T + 4096;
  float* out  = (float*)d_out;

  preT_kernel<<<64, 256, 0, stream>>>(
      maa_w1, maa_w2, dec_w1, dec_w2, w1T, w2T, d1T, d2T);

  prep_fused_kernel<<<BT / 128, 256, 0, stream>>>(
      x, tm_x, tm_w, tm_k, tm_v, tm_r, tm_g,
      w1T, w2T, d1T, d2T, t_decay, u,
      Wr, Wk, Wv, Wg, rkdc, v_o, g_o);

  chunkA_mfma_kernel<<<(BB * NCH) / 2, 128, 0, stream>>>(
      (const float4*)rkdc, v_o, scb, Dp);

  combine_kernel<<<BB, 1024, 0, stream>>>(scb, Dp);

  scanC_mfma_kernel<<<(BB * NCH) / 2, 128, 0, stream>>>(
      (const float4*)rkdc, v_o, scb, g_o, ln_w, ln_b, Wo, out);
}